// Round 1
// baseline (2285.546 us; speedup 1.0000x reference)
//
#include <hip/hip_runtime.h>

// ---------------------------------------------------------------------------
// MoNet GNN: N=50000 nodes, E=800000 edges, H=128, K=3, L=4, pdim=2, G=50
// Round 1: correct fp32 baseline.
//   h = x@emb_W+b
//   deg = indeg(dst); pseudo = [rsqrt(deg[src]+1), rsqrt(deg[dst]+1)]
//   gw[l][e][k] = exp(-0.5*||(tanh(pseudo@ppW[l]+ppb[l]) - mu[l,k])*isig[l,k]||^2)
//     (topology-only -> precompute once for all layers)
//   per layer: hp = h@fcW[l]+fcb[l] (N,3,128); agg[dst] += sum_k gw_k*hp[src,k,:]
//              BN(batch stats) -> relu -> residual
//   readout: per-graph mean -> 3-layer MLP -> out [G,10]
// ---------------------------------------------------------------------------

#define H 128

// ---- GEMM: C[M,N] = A[M,128] @ B[128,N] + bias[N].  64x64 tile, 4x4/thread.
__global__ __launch_bounds__(256) void gemm64(const float* __restrict__ A,
                                              const float* __restrict__ B,
                                              const float* __restrict__ bias,
                                              float* __restrict__ C,
                                              int M, int N) {
    __shared__ float As[128][68];   // transposed A tile: As[k][m], pad->16B aligned rows
    __shared__ float Bs[128][64];
    const int m0 = blockIdx.x * 64;
    const int n0 = blockIdx.y * 64;
    const int tid = threadIdx.x;

    // load A tile (64 rows x 128 k) as float4 along k, store transposed
#pragma unroll
    for (int i = 0; i < 8; i++) {
        int idx = tid + i * 256;          // 0..2047
        int row = idx >> 5;               // 0..63
        int kq  = idx & 31;               // 0..31
        float4 v = make_float4(0.f, 0.f, 0.f, 0.f);
        if (m0 + row < M) v = *(const float4*)(A + (size_t)(m0 + row) * 128 + kq * 4);
        As[kq * 4 + 0][row] = v.x;
        As[kq * 4 + 1][row] = v.y;
        As[kq * 4 + 2][row] = v.z;
        As[kq * 4 + 3][row] = v.w;
    }
    // load B tile (128 k x 64 cols)
#pragma unroll
    for (int i = 0; i < 8; i++) {
        int idx = tid + i * 256;
        int row = idx >> 4;               // 0..127
        int cq  = idx & 15;               // 0..15
        *(float4*)(&Bs[row][cq * 4]) = *(const float4*)(B + (size_t)row * N + n0 + cq * 4);
    }
    __syncthreads();

    const int tx = tid & 15, ty = tid >> 4;
    const int r0 = ty * 4, c0 = tx * 4;
    float acc[4][4] = {};
#pragma unroll 4
    for (int k = 0; k < 128; k++) {
        float4 a = *(const float4*)(&As[k][r0]);
        float4 b = *(const float4*)(&Bs[k][c0]);
        acc[0][0] += a.x * b.x; acc[0][1] += a.x * b.y; acc[0][2] += a.x * b.z; acc[0][3] += a.x * b.w;
        acc[1][0] += a.y * b.x; acc[1][1] += a.y * b.y; acc[1][2] += a.y * b.z; acc[1][3] += a.y * b.w;
        acc[2][0] += a.z * b.x; acc[2][1] += a.z * b.y; acc[2][2] += a.z * b.z; acc[2][3] += a.z * b.w;
        acc[3][0] += a.w * b.x; acc[3][1] += a.w * b.y; acc[3][2] += a.w * b.z; acc[3][3] += a.w * b.w;
    }
    float4 bv = *(const float4*)(bias + n0 + c0);
#pragma unroll
    for (int i = 0; i < 4; i++) {
        int row = m0 + r0 + i;
        if (row < M) {
            float4 o = make_float4(acc[i][0] + bv.x, acc[i][1] + bv.y,
                                   acc[i][2] + bv.z, acc[i][3] + bv.w);
            *(float4*)(C + (size_t)row * N + n0 + c0) = o;
        }
    }
}

// ---- in-degree
__global__ void deg_kernel(const int* __restrict__ dst, float* __restrict__ deg, int E) {
    int e = blockIdx.x * 256 + threadIdx.x;
    if (e < E) atomicAdd(&deg[dst[e]], 1.0f);
}

// ---- per-edge Gaussian weights for all L layers (topology-only)
__global__ void gw_kernel(const int* __restrict__ src, const int* __restrict__ dst,
                          const float* __restrict__ deg,
                          const float* __restrict__ ppW, const float* __restrict__ ppb,
                          const float* __restrict__ mu, const float* __restrict__ isig,
                          float* __restrict__ gw, int E, int L) {
    int e = blockIdx.x * 256 + threadIdx.x;
    if (e >= E) return;
    float ps0 = rsqrtf(deg[src[e]] + 1.0f);
    float ps1 = rsqrtf(deg[dst[e]] + 1.0f);
    for (int l = 0; l < L; l++) {
        // p_j = tanh(ps0*ppW[l,0,j] + ps1*ppW[l,1,j] + ppb[l,j]), pdim=2
        float p0 = tanhf(ps0 * ppW[l * 4 + 0] + ps1 * ppW[l * 4 + 2] + ppb[l * 2 + 0]);
        float p1 = tanhf(ps0 * ppW[l * 4 + 1] + ps1 * ppW[l * 4 + 3] + ppb[l * 2 + 1]);
#pragma unroll
        for (int k = 0; k < 3; k++) {
            float d0 = (p0 - mu[(l * 3 + k) * 2 + 0]) * isig[(l * 3 + k) * 2 + 0];
            float d1 = (p1 - mu[(l * 3 + k) * 2 + 1]) * isig[(l * 3 + k) * 2 + 1];
            gw[((size_t)l * E + e) * 3 + k] = expf(-0.5f * (d0 * d0 + d1 * d1));
        }
    }
}

// ---- message + scatter: agg[dst] += sum_k gw_k * hp[src,k,:]
__global__ __launch_bounds__(256) void message_kernel(const float* __restrict__ hp,
                                                      const float* __restrict__ gw,
                                                      const int* __restrict__ src,
                                                      const int* __restrict__ dst,
                                                      float* __restrict__ agg, int E) {
    int e = blockIdx.x * 2 + (threadIdx.x >> 7);
    if (e >= E) return;
    int c = threadIdx.x & 127;
    int s = src[e], d = dst[e];
    float g0 = gw[(size_t)e * 3 + 0];
    float g1 = gw[(size_t)e * 3 + 1];
    float g2 = gw[(size_t)e * 3 + 2];
    const float* base = hp + (size_t)s * 384;
    float m = g0 * base[c] + g1 * base[128 + c] + g2 * base[256 + c];
    atomicAdd(&agg[(size_t)d * 128 + c], m);
}

// ---- BN stats: per-channel sum & sumsq (atomics per block)
__global__ void bn_stats(const float* __restrict__ agg, float* __restrict__ bn, int N) {
    int c = threadIdx.x;       // 128
    int r0 = blockIdx.x * 256;
    float s = 0.f, s2 = 0.f;
    int r1 = min(r0 + 256, N);
    for (int r = r0; r < r1; r++) {
        float v = agg[(size_t)r * 128 + c];
        s += v; s2 += v * v;
    }
    atomicAdd(&bn[c], s);
    atomicAdd(&bn[128 + c], s2);
}

__global__ void bn_finalize(float* __restrict__ bn, const float* __restrict__ gamma,
                            const float* __restrict__ beta, int N) {
    int c = threadIdx.x;   // 128
    float invN = 1.0f / (float)N;
    float mean = bn[c] * invN;
    float var  = bn[128 + c] * invN - mean * mean;
    float scale = gamma[c] * rsqrtf(var + 1e-5f);
    bn[256 + c] = scale;
    bn[384 + c] = beta[c] - mean * scale;
}

// ---- h = h + relu(agg*scale + shift), vectorized float4
__global__ void bn_apply(float* __restrict__ h, const float* __restrict__ agg,
                         const float* __restrict__ bn, int N) {
    int idx = blockIdx.x * 256 + threadIdx.x;   // float4 index
    if (idx >= N * 32) return;
    int c4 = idx & 31;
    float4 a  = ((const float4*)agg)[idx];
    float4 sc = *(const float4*)(bn + 256 + c4 * 4);
    float4 sh = *(const float4*)(bn + 384 + c4 * 4);
    float4 hv = ((float4*)h)[idx];
    hv.x += fmaxf(a.x * sc.x + sh.x, 0.f);
    hv.y += fmaxf(a.y * sc.y + sh.y, 0.f);
    hv.z += fmaxf(a.z * sc.z + sh.z, 0.f);
    hv.w += fmaxf(a.w * sc.w + sh.w, 0.f);
    ((float4*)h)[idx] = hv;
}

// ---- per-graph sums (graph_ids sorted in the given data; flush-on-change)
__global__ void readout_kernel(const float* __restrict__ h, const int* __restrict__ gids,
                               float* __restrict__ hg, float* __restrict__ cnts, int N) {
    int c = threadIdx.x;    // 128
    int r0 = blockIdx.x * 250;
    if (r0 >= N) return;
    int r1 = min(r0 + 250, N);
    int cur = gids[r0];
    float acc = 0.f, cnt = 0.f;
    for (int r = r0; r < r1; r++) {
        int g = gids[r];
        if (g != cur) {
            atomicAdd(&hg[(size_t)cur * 128 + c], acc);
            if (c == 0) atomicAdd(&cnts[cur], cnt);
            acc = 0.f; cnt = 0.f; cur = g;
        }
        acc += h[(size_t)r * 128 + c];
        cnt += 1.f;
    }
    atomicAdd(&hg[(size_t)cur * 128 + c], acc);
    if (c == 0) atomicAdd(&cnts[cur], cnt);
}

// ---- MLP readout: one block per graph
__global__ void mlp_kernel(const float* __restrict__ hg, const float* __restrict__ cnts,
                           const float* __restrict__ W1, const float* __restrict__ b1,
                           const float* __restrict__ W2, const float* __restrict__ b2,
                           const float* __restrict__ W3, const float* __restrict__ b3,
                           float* __restrict__ out) {
    __shared__ float v[128], y1[64], y2[32];
    int g = blockIdx.x, t = threadIdx.x;
    float inv = 1.0f / cnts[g];
    v[t] = hg[(size_t)g * 128 + t] * inv;
    __syncthreads();
    if (t < 64) {
        float a = b1[t];
        for (int k = 0; k < 128; k++) a += v[k] * W1[k * 64 + t];
        y1[t] = fmaxf(a, 0.f);
    }
    __syncthreads();
    if (t < 32) {
        float a = b2[t];
        for (int k = 0; k < 64; k++) a += y1[k] * W2[k * 32 + t];
        y2[t] = fmaxf(a, 0.f);
    }
    __syncthreads();
    if (t < 10) {
        float a = b3[t];
        for (int k = 0; k < 32; k++) a += y2[k] * W3[k * 10 + t];
        out[g * 10 + t] = a;
    }
}

extern "C" void kernel_launch(void* const* d_in, const int* in_sizes, int n_in,
                              void* d_out, int out_size, void* d_ws, size_t ws_size,
                              hipStream_t stream) {
    const float* x      = (const float*)d_in[0];
    const float* emb_W  = (const float*)d_in[1];
    const float* emb_b  = (const float*)d_in[2];
    const float* fc_W   = (const float*)d_in[3];
    const float* fc_b   = (const float*)d_in[4];
    const float* mu     = (const float*)d_in[5];
    const float* isig   = (const float*)d_in[6];
    const float* gamma  = (const float*)d_in[7];
    const float* beta   = (const float*)d_in[8];
    const float* ppW    = (const float*)d_in[9];
    const float* ppb    = (const float*)d_in[10];
    const float* W1     = (const float*)d_in[11];
    const float* b1     = (const float*)d_in[12];
    const float* W2     = (const float*)d_in[13];
    const float* b2     = (const float*)d_in[14];
    const float* W3     = (const float*)d_in[15];
    const float* b3     = (const float*)d_in[16];
    const int*   src    = (const int*)d_in[17];
    const int*   dst    = (const int*)d_in[18];
    const int*   gids   = (const int*)d_in[19];

    const int N = in_sizes[0] / 128;       // in_dim = 128
    const int E = in_sizes[17];
    const int L = in_sizes[8] / 128;       // bn_beta [L,128]
    const int G = out_size / 10;           // n_classes = 10
    float* out = (float*)d_out;

    // workspace layout (256B aligned chunks)
    char* w = (char*)d_ws;
    auto alloc = [&](size_t bytes) {
        char* p = w;
        w += (bytes + 255) & ~(size_t)255;
        return (float*)p;
    };
    float* h    = alloc((size_t)N * 128 * 4);
    float* agg  = alloc((size_t)N * 128 * 4);
    float* hp   = alloc((size_t)N * 384 * 4);
    float* gw   = alloc((size_t)L * E * 3 * 4);
    float* deg  = alloc((size_t)N * 4);
    float* bn   = alloc(512 * 4);
    float* hg   = alloc((size_t)G * 128 * 4);
    float* cnts = alloc((size_t)G * 4);

    // zero what we accumulate into
    hipMemsetAsync(deg, 0, (size_t)N * 4, stream);
    hipMemsetAsync(hg, 0, (size_t)G * 128 * 4, stream);
    hipMemsetAsync(cnts, 0, (size_t)G * 4, stream);

    // node embedding
    {
        dim3 grid((N + 63) / 64, 128 / 64);
        gemm64<<<grid, 256, 0, stream>>>(x, emb_W, emb_b, h, N, 128);
    }
    // degrees + per-edge Gaussian weights for all layers
    deg_kernel<<<(E + 255) / 256, 256, 0, stream>>>(dst, deg, E);
    gw_kernel<<<(E + 255) / 256, 256, 0, stream>>>(src, dst, deg, ppW, ppb, mu, isig, gw, E, L);

    for (int l = 0; l < L; l++) {
        // hp = h @ fc_W[l] + fc_b[l]   [N, 384]
        dim3 grid((N + 63) / 64, 384 / 64);
        gemm64<<<grid, 256, 0, stream>>>(h, fc_W + (size_t)l * 128 * 384, fc_b + l * 384, hp, N, 384);

        hipMemsetAsync(agg, 0, (size_t)N * 128 * 4, stream);
        message_kernel<<<(E + 1) / 2, 256, 0, stream>>>(hp, gw + (size_t)l * E * 3, src, dst, agg, E);

        hipMemsetAsync(bn, 0, 256 * 4, stream);
        bn_stats<<<(N + 255) / 256, 128, 0, stream>>>(agg, bn, N);
        bn_finalize<<<1, 128, 0, stream>>>(bn, gamma + l * 128, beta + l * 128, N);
        bn_apply<<<(N * 32 + 255) / 256, 256, 0, stream>>>(h, agg, bn, N);
    }

    readout_kernel<<<(N + 249) / 250, 128, 0, stream>>>(h, gids, hg, cnts, N);
    mlp_kernel<<<G, 128, 0, stream>>>(hg, cnts, W1, b1, W2, b2, W3, b3, out);
}

// Round 2
// 1755.437 us; speedup vs baseline: 1.3020x; 1.3020x over previous
//
#include <hip/hip_runtime.h>

// ---------------------------------------------------------------------------
// MoNet GNN: N=50000, E=800000, H=128, K=3, L=4, pdim=2, G=50
// Round 2: dst-sorted CSR + algebraic reorder.
//   agg[d] = sum_k (sum_{e->d} gw_ek * h[src_e]) @ W_k + (sum_{e->d} gw_ek) * b_k
//   -> aggregate h (512B/edge) instead of hp (1536B/edge), no atomics
//      (register accumulation per node via CSR), GEMM moved after aggregation.
// ---------------------------------------------------------------------------

// ---- GEMM: C[M,N] = A[M,128] @ B[128,N] + bias[N].  64x64 tile, 4x4/thread.
__global__ __launch_bounds__(256) void gemm64(const float* __restrict__ A,
                                              const float* __restrict__ B,
                                              const float* __restrict__ bias,
                                              float* __restrict__ C,
                                              int M, int N) {
    __shared__ float As[128][68];
    __shared__ float Bs[128][64];
    const int m0 = blockIdx.x * 64;
    const int n0 = blockIdx.y * 64;
    const int tid = threadIdx.x;

#pragma unroll
    for (int i = 0; i < 8; i++) {
        int idx = tid + i * 256;
        int row = idx >> 5;
        int kq  = idx & 31;
        float4 v = make_float4(0.f, 0.f, 0.f, 0.f);
        if (m0 + row < M) v = *(const float4*)(A + (size_t)(m0 + row) * 128 + kq * 4);
        As[kq * 4 + 0][row] = v.x;
        As[kq * 4 + 1][row] = v.y;
        As[kq * 4 + 2][row] = v.z;
        As[kq * 4 + 3][row] = v.w;
    }
#pragma unroll
    for (int i = 0; i < 8; i++) {
        int idx = tid + i * 256;
        int row = idx >> 4;
        int cq  = idx & 15;
        *(float4*)(&Bs[row][cq * 4]) = *(const float4*)(B + (size_t)row * N + n0 + cq * 4);
    }
    __syncthreads();

    const int tx = tid & 15, ty = tid >> 4;
    const int r0 = ty * 4, c0 = tx * 4;
    float acc[4][4] = {};
#pragma unroll 4
    for (int k = 0; k < 128; k++) {
        float4 a = *(const float4*)(&As[k][r0]);
        float4 b = *(const float4*)(&Bs[k][c0]);
        acc[0][0] += a.x * b.x; acc[0][1] += a.x * b.y; acc[0][2] += a.x * b.z; acc[0][3] += a.x * b.w;
        acc[1][0] += a.y * b.x; acc[1][1] += a.y * b.y; acc[1][2] += a.y * b.z; acc[1][3] += a.y * b.w;
        acc[2][0] += a.z * b.x; acc[2][1] += a.z * b.y; acc[2][2] += a.z * b.z; acc[2][3] += a.z * b.w;
        acc[3][0] += a.w * b.x; acc[3][1] += a.w * b.y; acc[3][2] += a.w * b.z; acc[3][3] += a.w * b.w;
    }
    float4 bv = *(const float4*)(bias + n0 + c0);
#pragma unroll
    for (int i = 0; i < 4; i++) {
        int row = m0 + r0 + i;
        if (row < M) {
            float4 o = make_float4(acc[i][0] + bv.x, acc[i][1] + bv.y,
                                   acc[i][2] + bv.z, acc[i][3] + bv.w);
            *(float4*)(C + (size_t)row * N + n0 + c0) = o;
        }
    }
}

// ---- GEMM for reordered fc: C[M,128] = t[M,384] @ B'[384,128] + sk-weighted bias
//      B'[kc*128+r, o] = fcW[r*384 + kc*128 + o]
__global__ __launch_bounds__(256) void gemm_fc(const float* __restrict__ A,   // t [M,384]
                                               const float* __restrict__ W,   // fcW[l] [128,384]
                                               const float* __restrict__ b,   // fcb[l] [384]
                                               const float* __restrict__ sk,  // [M,4]
                                               float* __restrict__ C,         // agg [M,128]
                                               int M) {
    __shared__ float As[128][68];
    __shared__ float Bs[128][64];
    const int m0 = blockIdx.x * 64;
    const int n0 = blockIdx.y * 64;
    const int tid = threadIdx.x;
    const int tx = tid & 15, ty = tid >> 4;
    const int r0 = ty * 4, c0 = tx * 4;
    float acc[4][4] = {};

    for (int kc = 0; kc < 3; kc++) {
        __syncthreads();
#pragma unroll
        for (int i = 0; i < 8; i++) {
            int idx = tid + i * 256;
            int row = idx >> 5;
            int kq  = idx & 31;
            float4 v = make_float4(0.f, 0.f, 0.f, 0.f);
            if (m0 + row < M)
                v = *(const float4*)(A + (size_t)(m0 + row) * 384 + kc * 128 + kq * 4);
            As[kq * 4 + 0][row] = v.x;
            As[kq * 4 + 1][row] = v.y;
            As[kq * 4 + 2][row] = v.z;
            As[kq * 4 + 3][row] = v.w;
        }
#pragma unroll
        for (int i = 0; i < 8; i++) {
            int idx = tid + i * 256;
            int r  = idx >> 4;
            int cq = idx & 15;
            *(float4*)(&Bs[r][cq * 4]) = *(const float4*)(W + (size_t)r * 384 + kc * 128 + n0 + cq * 4);
        }
        __syncthreads();
#pragma unroll 4
        for (int k = 0; k < 128; k++) {
            float4 a  = *(const float4*)(&As[k][r0]);
            float4 bb = *(const float4*)(&Bs[k][c0]);
            acc[0][0] += a.x * bb.x; acc[0][1] += a.x * bb.y; acc[0][2] += a.x * bb.z; acc[0][3] += a.x * bb.w;
            acc[1][0] += a.y * bb.x; acc[1][1] += a.y * bb.y; acc[1][2] += a.y * bb.z; acc[1][3] += a.y * bb.w;
            acc[2][0] += a.z * bb.x; acc[2][1] += a.z * bb.y; acc[2][2] += a.z * bb.z; acc[2][3] += a.z * bb.w;
            acc[3][0] += a.w * bb.x; acc[3][1] += a.w * bb.y; acc[3][2] += a.w * bb.z; acc[3][3] += a.w * bb.w;
        }
    }
    float4 b0 = *(const float4*)(b +   0 + n0 + c0);
    float4 b1 = *(const float4*)(b + 128 + n0 + c0);
    float4 b2 = *(const float4*)(b + 256 + n0 + c0);
#pragma unroll
    for (int i = 0; i < 4; i++) {
        int row = m0 + r0 + i;
        if (row < M) {
            float s0 = sk[row * 4 + 0], s1 = sk[row * 4 + 1], s2 = sk[row * 4 + 2];
            float4 o;
            o.x = acc[i][0] + s0 * b0.x + s1 * b1.x + s2 * b2.x;
            o.y = acc[i][1] + s0 * b0.y + s1 * b1.y + s2 * b2.y;
            o.z = acc[i][2] + s0 * b0.z + s1 * b1.z + s2 * b2.z;
            o.w = acc[i][3] + s0 * b0.w + s1 * b1.w + s2 * b2.w;
            *(float4*)(C + (size_t)row * 128 + n0 + c0) = o;
        }
    }
}

// ---- in-degree histogram (int)
__global__ void hist_kernel(const int* __restrict__ dst, int* __restrict__ cnt, int E) {
    int e = blockIdx.x * 256 + threadIdx.x;
    if (e < E) atomicAdd(&cnt[dst[e]], 1);
}

// ---- exclusive scan over cnt -> rs[0..N], single block
__global__ __launch_bounds__(1024) void scan_kernel(const int* __restrict__ cnt,
                                                    int* __restrict__ rs, int N) {
    __shared__ int buf[1024];
    __shared__ int carry;
    int t = threadIdx.x;
    if (t == 0) { carry = 0; rs[0] = 0; }
    __syncthreads();
    for (int base = 0; base < N; base += 1024) {
        int v = (base + t < N) ? cnt[base + t] : 0;
        buf[t] = v;
        __syncthreads();
        for (int off = 1; off < 1024; off <<= 1) {
            int x = (t >= off) ? buf[t - off] : 0;
            __syncthreads();
            buf[t] += x;
            __syncthreads();
        }
        int incl = buf[t] + carry;
        if (base + t < N) rs[base + t + 1] = incl;
        __syncthreads();
        if (t == 1023) carry = incl;
        __syncthreads();
    }
}

// ---- scatter edges into dst-sorted order
__global__ void scatter_kernel(const int* __restrict__ src, const int* __restrict__ dst,
                               const int* __restrict__ rs, int* __restrict__ cursor,
                               int* __restrict__ epos, int* __restrict__ psrc, int E) {
    int e = blockIdx.x * 256 + threadIdx.x;
    if (e >= E) return;
    int d = dst[e];
    int pos = rs[d] + atomicAdd(&cursor[d], 1);
    epos[pos] = e;
    psrc[pos] = src[e];
}

// ---- per-edge Gaussian weights for all L layers (edge order, coalesced)
__global__ void gw_kernel(const int* __restrict__ src, const int* __restrict__ dst,
                          const int* __restrict__ cnt,
                          const float* __restrict__ ppW, const float* __restrict__ ppb,
                          const float* __restrict__ mu, const float* __restrict__ isig,
                          float* __restrict__ gw, int E, int L) {
    int e = blockIdx.x * 256 + threadIdx.x;
    if (e >= E) return;
    float ps0 = rsqrtf((float)cnt[src[e]] + 1.0f);
    float ps1 = rsqrtf((float)cnt[dst[e]] + 1.0f);
    for (int l = 0; l < L; l++) {
        float p0 = tanhf(ps0 * ppW[l * 4 + 0] + ps1 * ppW[l * 4 + 2] + ppb[l * 2 + 0]);
        float p1 = tanhf(ps0 * ppW[l * 4 + 1] + ps1 * ppW[l * 4 + 3] + ppb[l * 2 + 1]);
#pragma unroll
        for (int k = 0; k < 3; k++) {
            float d0 = (p0 - mu[(l * 3 + k) * 2 + 0]) * isig[(l * 3 + k) * 2 + 0];
            float d1 = (p1 - mu[(l * 3 + k) * 2 + 1]) * isig[(l * 3 + k) * 2 + 1];
            gw[((size_t)l * E + e) * 3 + k] = expf(-0.5f * (d0 * d0 + d1 * d1));
        }
    }
}

// ---- per-node weighted aggregation of h into t (no atomics)
//      t[n, k*128+c] = sum_{e->n} gw_ek * h[src_e, c];  sk[n,k] = sum_{e->n} gw_ek
__global__ __launch_bounds__(256) void agg_kernel(const float* __restrict__ h,
                                                  const float* __restrict__ gw,  // layer base, e-indexed
                                                  const int* __restrict__ epos,
                                                  const int* __restrict__ psrc,
                                                  const int* __restrict__ rs,
                                                  float* __restrict__ t,
                                                  float* __restrict__ sk, int N) {
    int nid = blockIdx.x * 2 + (threadIdx.x >> 7);
    if (nid >= N) return;
    int c = threadIdx.x & 127;
    int p0 = rs[nid], p1 = rs[nid + 1];
    float a0 = 0.f, a1 = 0.f, a2 = 0.f;
    float g0s = 0.f, g1s = 0.f, g2s = 0.f;
    for (int p = p0; p < p1; p++) {
        int e = epos[p];
        int s = psrc[p];
        float g0 = gw[(size_t)e * 3 + 0];
        float g1 = gw[(size_t)e * 3 + 1];
        float g2 = gw[(size_t)e * 3 + 2];
        float m  = h[(size_t)s * 128 + c];
        a0 += g0 * m; a1 += g1 * m; a2 += g2 * m;
        g0s += g0; g1s += g1; g2s += g2;
    }
    size_t base = (size_t)nid * 384;
    t[base + c]       = a0;
    t[base + 128 + c] = a1;
    t[base + 256 + c] = a2;
    if (c == 0) {
        sk[nid * 4 + 0] = g0s;
        sk[nid * 4 + 1] = g1s;
        sk[nid * 4 + 2] = g2s;
    }
}

// ---- BN stats: per-channel sum & sumsq
__global__ void bn_stats(const float* __restrict__ agg, float* __restrict__ bn, int N) {
    int c = threadIdx.x;       // 128
    int r0 = blockIdx.x * 64;
    int r1 = min(r0 + 64, N);
    float s = 0.f, s2 = 0.f;
    for (int r = r0; r < r1; r++) {
        float v = agg[(size_t)r * 128 + c];
        s += v; s2 += v * v;
    }
    atomicAdd(&bn[c], s);
    atomicAdd(&bn[128 + c], s2);
}

__global__ void bn_finalize(float* __restrict__ bn, const float* __restrict__ gamma,
                            const float* __restrict__ beta, int N) {
    int c = threadIdx.x;
    float invN = 1.0f / (float)N;
    float mean = bn[c] * invN;
    float var  = bn[128 + c] * invN - mean * mean;
    float scale = gamma[c] * rsqrtf(var + 1e-5f);
    bn[256 + c] = scale;
    bn[384 + c] = beta[c] - mean * scale;
}

// ---- h = h + relu(agg*scale + shift)
__global__ void bn_apply(float* __restrict__ h, const float* __restrict__ agg,
                         const float* __restrict__ bn, int N) {
    int idx = blockIdx.x * 256 + threadIdx.x;
    if (idx >= N * 32) return;
    int c4 = idx & 31;
    float4 a  = ((const float4*)agg)[idx];
    float4 sc = *(const float4*)(bn + 256 + c4 * 4);
    float4 sh = *(const float4*)(bn + 384 + c4 * 4);
    float4 hv = ((float4*)h)[idx];
    hv.x += fmaxf(a.x * sc.x + sh.x, 0.f);
    hv.y += fmaxf(a.y * sc.y + sh.y, 0.f);
    hv.z += fmaxf(a.z * sc.z + sh.z, 0.f);
    hv.w += fmaxf(a.w * sc.w + sh.w, 0.f);
    ((float4*)h)[idx] = hv;
}

// ---- per-graph sums (graph_ids sorted; flush-on-change)
__global__ void readout_kernel(const float* __restrict__ h, const int* __restrict__ gids,
                               float* __restrict__ hg, float* __restrict__ cnts, int N) {
    int c = threadIdx.x;
    int r0 = blockIdx.x * 250;
    if (r0 >= N) return;
    int r1 = min(r0 + 250, N);
    int cur = gids[r0];
    float acc = 0.f, cnt = 0.f;
    for (int r = r0; r < r1; r++) {
        int g = gids[r];
        if (g != cur) {
            atomicAdd(&hg[(size_t)cur * 128 + c], acc);
            if (c == 0) atomicAdd(&cnts[cur], cnt);
            acc = 0.f; cnt = 0.f; cur = g;
        }
        acc += h[(size_t)r * 128 + c];
        cnt += 1.f;
    }
    atomicAdd(&hg[(size_t)cur * 128 + c], acc);
    if (c == 0) atomicAdd(&cnts[cur], cnt);
}

// ---- MLP readout
__global__ void mlp_kernel(const float* __restrict__ hg, const float* __restrict__ cnts,
                           const float* __restrict__ W1, const float* __restrict__ b1,
                           const float* __restrict__ W2, const float* __restrict__ b2,
                           const float* __restrict__ W3, const float* __restrict__ b3,
                           float* __restrict__ out) {
    __shared__ float v[128], y1[64], y2[32];
    int g = blockIdx.x, t = threadIdx.x;
    float inv = 1.0f / cnts[g];
    v[t] = hg[(size_t)g * 128 + t] * inv;
    __syncthreads();
    if (t < 64) {
        float a = b1[t];
        for (int k = 0; k < 128; k++) a += v[k] * W1[k * 64 + t];
        y1[t] = fmaxf(a, 0.f);
    }
    __syncthreads();
    if (t < 32) {
        float a = b2[t];
        for (int k = 0; k < 64; k++) a += y1[k] * W2[k * 32 + t];
        y2[t] = fmaxf(a, 0.f);
    }
    __syncthreads();
    if (t < 10) {
        float a = b3[t];
        for (int k = 0; k < 32; k++) a += y2[k] * W3[k * 10 + t];
        out[g * 10 + t] = a;
    }
}

extern "C" void kernel_launch(void* const* d_in, const int* in_sizes, int n_in,
                              void* d_out, int out_size, void* d_ws, size_t ws_size,
                              hipStream_t stream) {
    const float* x      = (const float*)d_in[0];
    const float* emb_W  = (const float*)d_in[1];
    const float* emb_b  = (const float*)d_in[2];
    const float* fc_W   = (const float*)d_in[3];
    const float* fc_b   = (const float*)d_in[4];
    const float* mu     = (const float*)d_in[5];
    const float* isig   = (const float*)d_in[6];
    const float* gamma  = (const float*)d_in[7];
    const float* beta   = (const float*)d_in[8];
    const float* ppW    = (const float*)d_in[9];
    const float* ppb    = (const float*)d_in[10];
    const float* W1     = (const float*)d_in[11];
    const float* b1     = (const float*)d_in[12];
    const float* W2     = (const float*)d_in[13];
    const float* b2     = (const float*)d_in[14];
    const float* W3     = (const float*)d_in[15];
    const float* b3     = (const float*)d_in[16];
    const int*   src    = (const int*)d_in[17];
    const int*   dst    = (const int*)d_in[18];
    const int*   gids   = (const int*)d_in[19];

    const int N = in_sizes[0] / 128;
    const int E = in_sizes[17];
    const int L = in_sizes[8] / 128;
    const int G = out_size / 10;
    float* out = (float*)d_out;

    char* w = (char*)d_ws;
    auto alloc = [&](size_t bytes) {
        char* p = w;
        w += (bytes + 255) & ~(size_t)255;
        return (void*)p;
    };
    float* h      = (float*)alloc((size_t)N * 128 * 4);
    float* t      = (float*)alloc((size_t)N * 384 * 4);
    float* agg    = (float*)alloc((size_t)N * 128 * 4);
    float* gw     = (float*)alloc((size_t)L * E * 3 * 4);
    int*   epos   = (int*)alloc((size_t)E * 4);
    int*   psrc   = (int*)alloc((size_t)E * 4);
    float* sk     = (float*)alloc((size_t)N * 4 * 4);
    int*   cnt    = (int*)alloc((size_t)N * 4);
    int*   rs     = (int*)alloc((size_t)(N + 1) * 4);
    int*   cursor = (int*)alloc((size_t)N * 4);
    float* bn     = (float*)alloc(512 * 4);
    float* hg     = (float*)alloc((size_t)G * 128 * 4);
    float* cnts   = (float*)alloc((size_t)G * 4);

    hipMemsetAsync(cnt, 0, (size_t)N * 4, stream);
    hipMemsetAsync(cursor, 0, (size_t)N * 4, stream);
    hipMemsetAsync(hg, 0, (size_t)G * 128 * 4, stream);
    hipMemsetAsync(cnts, 0, (size_t)G * 4, stream);

    // node embedding: h = x @ emb_W + emb_b
    {
        dim3 grid((N + 63) / 64, 128 / 64);
        gemm64<<<grid, 256, 0, stream>>>(x, emb_W, emb_b, h, N, 128);
    }
    // CSR build + per-edge Gaussian weights (topology-only, all layers)
    hist_kernel<<<(E + 255) / 256, 256, 0, stream>>>(dst, cnt, E);
    scan_kernel<<<1, 1024, 0, stream>>>(cnt, rs, N);
    scatter_kernel<<<(E + 255) / 256, 256, 0, stream>>>(src, dst, rs, cursor, epos, psrc, E);
    gw_kernel<<<(E + 255) / 256, 256, 0, stream>>>(src, dst, cnt, ppW, ppb, mu, isig, gw, E, L);

    for (int l = 0; l < L; l++) {
        agg_kernel<<<(N + 1) / 2, 256, 0, stream>>>(h, gw + (size_t)l * E * 3, epos, psrc, rs, t, sk, N);
        {
            dim3 grid((N + 63) / 64, 2);
            gemm_fc<<<grid, 256, 0, stream>>>(t, fc_W + (size_t)l * 128 * 384, fc_b + (size_t)l * 384,
                                              sk, agg, N);
        }
        hipMemsetAsync(bn, 0, 256 * 4, stream);
        bn_stats<<<(N + 63) / 64, 128, 0, stream>>>(agg, bn, N);
        bn_finalize<<<1, 128, 0, stream>>>(bn, gamma + l * 128, beta + l * 128, N);
        bn_apply<<<(N * 32 + 255) / 256, 256, 0, stream>>>(h, agg, bn, N);
    }

    readout_kernel<<<(N + 249) / 250, 128, 0, stream>>>(h, gids, hg, cnts, N);
    mlp_kernel<<<G, 128, 0, stream>>>(hg, cnts, W1, b1, W2, b2, W3, b3, out);
}

// Round 3
// 718.634 us; speedup vs baseline: 3.1804x; 2.4427x over previous
//
#include <hip/hip_runtime.h>

// ---------------------------------------------------------------------------
// MoNet GNN: N=50000, E=800000, H=128, K=3, L=4, pdim=2, G=50
// Round 3: bf16 MFMA GEMMs + permuted-stream CSR aggregation (no indirection,
//          unroll-4 for MLP), bf16 h gather, reordered fc GEMM after agg.
// ---------------------------------------------------------------------------

typedef unsigned short u16;
typedef unsigned int   u32;
typedef __attribute__((ext_vector_type(8))) short bf16x8;
typedef __attribute__((ext_vector_type(4))) float f32x4;

__device__ __forceinline__ u16 f2b(float f) {
    union { float f; u32 u; } v; v.f = f;
    u32 u = v.u;
    u32 r = (u + 0x7fffu + ((u >> 16) & 1u)) >> 16;   // RNE
    return (u16)r;
}
__device__ __forceinline__ float blo(u32 h) {   // low bf16 -> f32
    union { u32 u; float f; } v; v.u = h << 16; return v.f;
}
__device__ __forceinline__ float bhi(u32 h) {   // high bf16 -> f32
    union { u32 u; float f; } v; v.u = h & 0xffff0000u; return v.f;
}

// ---- fp32 -> bf16 conversion (x4 per thread)
__global__ void cvt_bf16(const float* __restrict__ in, u16* __restrict__ out, int n4) {
    int i = blockIdx.x * 256 + threadIdx.x;
    if (i >= n4) return;
    float4 v = ((const float4*)in)[i];
    ushort4 o; o.x = f2b(v.x); o.y = f2b(v.y); o.z = f2b(v.z); o.w = f2b(v.w);
    ((ushort4*)out)[i] = o;
}

// ---- prep emb_W^T in bf16: Bt[n][k] = emb_W[k*128+n]
__global__ void prep_embW(const float* __restrict__ W, u16* __restrict__ Bt) {
    int idx = blockIdx.x * 256 + threadIdx.x;   // 16384
    int n = idx >> 7, k = idx & 127;
    Bt[idx] = f2b(W[k * 128 + n]);
}

// ---- prep fc weights: Bp[l][n][kc*128+r] = fcW[l][r][kc*128+n]  (bf16, B^T layout)
__global__ void prep_fcW(const float* __restrict__ W, u16* __restrict__ Bp, int total) {
    int idx = blockIdx.x * 256 + threadIdx.x;   // L*128*384
    if (idx >= total) return;
    int kk = idx % 384;
    int rest = idx / 384;
    int n = rest & 127;
    int l = rest >> 7;
    int kc = kk >> 7, r = kk & 127;
    Bp[idx] = f2b(W[((size_t)(l * 128 + r)) * 384 + kc * 128 + n]);
}

// ---- in-degree histogram
__global__ void hist_kernel(const int* __restrict__ dst, int* __restrict__ cnt, int E) {
    int e = blockIdx.x * 256 + threadIdx.x;
    if (e < E) atomicAdd(&cnt[dst[e]], 1);
}

// ---- 3-phase exclusive scan of cnt[N] -> rs[N+1]
__global__ void scan_partial(const int* __restrict__ cnt, int* __restrict__ bsum, int N) {
    __shared__ int buf[256];
    int t = threadIdx.x, base = blockIdx.x * 256;
    buf[t] = (base + t < N) ? cnt[base + t] : 0;
    __syncthreads();
    for (int off = 128; off > 0; off >>= 1) {
        if (t < off) buf[t] += buf[t + off];
        __syncthreads();
    }
    if (t == 0) bsum[blockIdx.x] = buf[0];
}
__global__ void scan_bsums(const int* __restrict__ bsum, int* __restrict__ boff, int nb) {
    __shared__ int buf[256];
    int t = threadIdx.x;
    int v = (t < nb) ? bsum[t] : 0;
    buf[t] = v;
    __syncthreads();
    for (int off = 1; off < 256; off <<= 1) {
        int x = (t >= off) ? buf[t - off] : 0;
        __syncthreads();
        buf[t] += x;
        __syncthreads();
    }
    if (t < nb) boff[t] = buf[t] - v;   // exclusive
}
__global__ void scan_final(const int* __restrict__ cnt, const int* __restrict__ boff,
                           int* __restrict__ rs, int N) {
    __shared__ int buf[256];
    int t = threadIdx.x, base = blockIdx.x * 256;
    int v = (base + t < N) ? cnt[base + t] : 0;
    buf[t] = v;
    __syncthreads();
    for (int off = 1; off < 256; off <<= 1) {
        int x = (t >= off) ? buf[t - off] : 0;
        __syncthreads();
        buf[t] += x;
        __syncthreads();
    }
    if (base + t < N) rs[base + t + 1] = boff[blockIdx.x] + buf[t];
    if (base == 0 && t == 0) rs[0] = 0;
}

// ---- scatter edges into dst-sorted order (store src and dst per position)
__global__ void scatter_kernel(const int* __restrict__ src, const int* __restrict__ dst,
                               const int* __restrict__ rs, int* __restrict__ cursor,
                               int* __restrict__ psrc, int* __restrict__ pdst, int E) {
    int e = blockIdx.x * 256 + threadIdx.x;
    if (e >= E) return;
    int d = dst[e];
    int pos = rs[d] + atomicAdd(&cursor[d], 1);
    psrc[pos] = src[e];
    pdst[pos] = d;
}

// ---- Gaussian weights in permuted (sorted) order, all L layers, padded float4
__global__ void gw_kernel(const int* __restrict__ psrc, const int* __restrict__ pdst,
                          const int* __restrict__ cnt,
                          const float* __restrict__ ppW, const float* __restrict__ ppb,
                          const float* __restrict__ mu, const float* __restrict__ isig,
                          float* __restrict__ pgw, int E, int L) {
    int p = blockIdx.x * 256 + threadIdx.x;
    if (p >= E) return;
    float ps0 = rsqrtf((float)cnt[psrc[p]] + 1.0f);
    float ps1 = rsqrtf((float)cnt[pdst[p]] + 1.0f);
    for (int l = 0; l < L; l++) {
        float p0 = tanhf(ps0 * ppW[l * 4 + 0] + ps1 * ppW[l * 4 + 2] + ppb[l * 2 + 0]);
        float p1 = tanhf(ps0 * ppW[l * 4 + 1] + ps1 * ppW[l * 4 + 3] + ppb[l * 2 + 1]);
        float4 o;
        float* ov = (float*)&o;
#pragma unroll
        for (int k = 0; k < 3; k++) {
            float d0 = (p0 - mu[(l * 3 + k) * 2 + 0]) * isig[(l * 3 + k) * 2 + 0];
            float d1 = (p1 - mu[(l * 3 + k) * 2 + 1]) * isig[(l * 3 + k) * 2 + 1];
            ov[k] = expf(-0.5f * (d0 * d0 + d1 * d1));
        }
        o.w = 0.f;
        ((float4*)pgw)[(size_t)l * E + p] = o;
    }
}

// ---- per-node aggregation: one wave per node, 2 channels per lane, unroll 4.
//      t[n][k*128+c] (bf16) = sum_e gw_ek * hb[src_e][c];  sk[n][k] = sum_e gw_ek
__global__ __launch_bounds__(256) void agg_kernel(const u16* __restrict__ hb,
                                                  const float* __restrict__ pgw,  // layer base
                                                  const int* __restrict__ psrc,
                                                  const int* __restrict__ rs,
                                                  u16* __restrict__ t,
                                                  float* __restrict__ sk, int N) {
    int nid = blockIdx.x * 4 + (threadIdx.x >> 6);
    if (nid >= N) return;
    int lane = threadIdx.x & 63;
    int p0 = rs[nid], p1 = rs[nid + 1];
    float a00 = 0.f, a01 = 0.f, a10 = 0.f, a11 = 0.f, a20 = 0.f, a21 = 0.f;
    float gs0 = 0.f, gs1 = 0.f, gs2 = 0.f;
    const float4* pg4 = (const float4*)pgw;
    int p = p0;
    for (; p + 4 <= p1; p += 4) {
        int s0 = psrc[p], s1 = psrc[p + 1], s2 = psrc[p + 2], s3 = psrc[p + 3];
        float4 g0 = pg4[p], g1 = pg4[p + 1], g2 = pg4[p + 2], g3 = pg4[p + 3];
        u32 h0 = *(const u32*)(hb + (size_t)s0 * 128 + lane * 2);
        u32 h1 = *(const u32*)(hb + (size_t)s1 * 128 + lane * 2);
        u32 h2 = *(const u32*)(hb + (size_t)s2 * 128 + lane * 2);
        u32 h3 = *(const u32*)(hb + (size_t)s3 * 128 + lane * 2);
        float f0l = blo(h0), f0h = bhi(h0);
        float f1l = blo(h1), f1h = bhi(h1);
        float f2l = blo(h2), f2h = bhi(h2);
        float f3l = blo(h3), f3h = bhi(h3);
        a00 += g0.x * f0l + g1.x * f1l + g2.x * f2l + g3.x * f3l;
        a01 += g0.x * f0h + g1.x * f1h + g2.x * f2h + g3.x * f3h;
        a10 += g0.y * f0l + g1.y * f1l + g2.y * f2l + g3.y * f3l;
        a11 += g0.y * f0h + g1.y * f1h + g2.y * f2h + g3.y * f3h;
        a20 += g0.z * f0l + g1.z * f1l + g2.z * f2l + g3.z * f3l;
        a21 += g0.z * f0h + g1.z * f1h + g2.z * f2h + g3.z * f3h;
        gs0 += g0.x + g1.x + g2.x + g3.x;
        gs1 += g0.y + g1.y + g2.y + g3.y;
        gs2 += g0.z + g1.z + g2.z + g3.z;
    }
    for (; p < p1; p++) {
        int s0 = psrc[p];
        float4 g0 = pg4[p];
        u32 h0 = *(const u32*)(hb + (size_t)s0 * 128 + lane * 2);
        float f0l = blo(h0), f0h = bhi(h0);
        a00 += g0.x * f0l; a01 += g0.x * f0h;
        a10 += g0.y * f0l; a11 += g0.y * f0h;
        a20 += g0.z * f0l; a21 += g0.z * f0h;
        gs0 += g0.x; gs1 += g0.y; gs2 += g0.z;
    }
    size_t base = (size_t)nid * 384 + lane * 2;
    *(u32*)(t + base)       = (u32)f2b(a00) | ((u32)f2b(a01) << 16);
    *(u32*)(t + base + 128) = (u32)f2b(a10) | ((u32)f2b(a11) << 16);
    *(u32*)(t + base + 256) = (u32)f2b(a20) | ((u32)f2b(a21) << 16);
    if (lane == 0) {
        sk[nid * 4 + 0] = gs0;
        sk[nid * 4 + 1] = gs1;
        sk[nid * 4 + 2] = gs2;
        sk[nid * 4 + 3] = 0.f;
    }
}

// ---- bf16 MFMA GEMM: out[M,128] = A[M,KD] @ Bt[128,KD]^T (+ epilogue)
//   mode 0 (embed): v = acc + bias[col]; h[row,col]=v; hb[row,col]=bf16(v)
//   mode 1 (fc):    v = acc + sum_k sk[row,k]*bias[k*128+col]; outF[row,col]=v
__global__ __launch_bounds__(256) void gemm_mfma(const u16* __restrict__ A,
                                                 const u16* __restrict__ Bt,
                                                 int M, int KD,
                                                 const float* __restrict__ bias,
                                                 const float* __restrict__ sk,
                                                 float* __restrict__ outF,
                                                 u16* __restrict__ outB,
                                                 int mode) {
    __shared__ u16 As[128 * 64];
    __shared__ u16 Bs[128 * 64];
    const int m0 = blockIdx.x * 128;
    const int tid = threadIdx.x;
    const int lane = tid & 63;
    const int w = tid >> 6;
    const int wr = w >> 1, wc = w & 1;

    f32x4 acc[4][4];
#pragma unroll
    for (int m = 0; m < 4; m++)
#pragma unroll
        for (int n = 0; n < 4; n++) acc[m][n] = (f32x4){0.f, 0.f, 0.f, 0.f};

    for (int k0 = 0; k0 < KD; k0 += 64) {
        __syncthreads();
#pragma unroll
        for (int i = 0; i < 4; i++) {
            int idx = tid + i * 256;        // 0..1023
            int r = idx >> 3, g = idx & 7;
            int gs = g ^ (r & 7);
            uint4 av = make_uint4(0, 0, 0, 0);
            if (m0 + r < M) av = *(const uint4*)(A + (size_t)(m0 + r) * KD + k0 + g * 8);
            *(uint4*)(As + r * 64 + gs * 8) = av;
            uint4 bv = *(const uint4*)(Bt + (size_t)r * KD + k0 + g * 8);
            *(uint4*)(Bs + r * 64 + gs * 8) = bv;
        }
        __syncthreads();
#pragma unroll
        for (int kk = 0; kk < 2; kk++) {
            bf16x8 af[4], bfr[4];
#pragma unroll
            for (int m = 0; m < 4; m++) {
                int r = wr * 64 + m * 16 + (lane & 15);
                int g = (kk * 4 + (lane >> 4)) ^ (r & 7);
                af[m] = *(const bf16x8*)(As + r * 64 + g * 8);
            }
#pragma unroll
            for (int n = 0; n < 4; n++) {
                int r = wc * 64 + n * 16 + (lane & 15);
                int g = (kk * 4 + (lane >> 4)) ^ (r & 7);
                bfr[n] = *(const bf16x8*)(Bs + r * 64 + g * 8);
            }
#pragma unroll
            for (int m = 0; m < 4; m++)
#pragma unroll
                for (int n = 0; n < 4; n++)
                    acc[m][n] = __builtin_amdgcn_mfma_f32_16x16x32_bf16(af[m], bfr[n], acc[m][n], 0, 0, 0);
        }
    }

    // epilogue: C/D layout col=lane&15, row=(lane>>4)*4+j
    if (mode == 0) {
#pragma unroll
        for (int n = 0; n < 4; n++) {
            int col = wc * 64 + n * 16 + (lane & 15);
            float bv = bias[col];
#pragma unroll
            for (int m = 0; m < 4; m++) {
#pragma unroll
                for (int j = 0; j < 4; j++) {
                    int row = m0 + wr * 64 + m * 16 + (lane >> 4) * 4 + j;
                    if (row < M) {
                        float v = acc[m][n][j] + bv;
                        outF[(size_t)row * 128 + col] = v;
                        outB[(size_t)row * 128 + col] = f2b(v);
                    }
                }
            }
        }
    } else {
#pragma unroll
        for (int n = 0; n < 4; n++) {
            int col = wc * 64 + n * 16 + (lane & 15);
            float b0 = bias[col], b1 = bias[128 + col], b2 = bias[256 + col];
#pragma unroll
            for (int m = 0; m < 4; m++) {
#pragma unroll
                for (int j = 0; j < 4; j++) {
                    int row = m0 + wr * 64 + m * 16 + (lane >> 4) * 4 + j;
                    if (row < M) {
                        float4 skv = *(const float4*)(sk + row * 4);
                        float v = acc[m][n][j] + skv.x * b0 + skv.y * b1 + skv.z * b2;
                        outF[(size_t)row * 128 + col] = v;
                    }
                }
            }
        }
    }
}

// ---- BN stats
__global__ void bn_stats(const float* __restrict__ agg, float* __restrict__ bn, int N) {
    int c = threadIdx.x;       // 128
    int r0 = blockIdx.x * 64;
    int r1 = min(r0 + 64, N);
    float s = 0.f, s2 = 0.f;
    for (int r = r0; r < r1; r++) {
        float v = agg[(size_t)r * 128 + c];
        s += v; s2 += v * v;
    }
    atomicAdd(&bn[c], s);
    atomicAdd(&bn[128 + c], s2);
}

__global__ void bn_finalize(float* __restrict__ bn, const float* __restrict__ gamma,
                            const float* __restrict__ beta, int N) {
    int c = threadIdx.x;
    float invN = 1.0f / (float)N;
    float mean = bn[c] * invN;
    float var  = bn[128 + c] * invN - mean * mean;
    float scale = gamma[c] * rsqrtf(var + 1e-5f);
    bn[256 + c] = scale;
    bn[384 + c] = beta[c] - mean * scale;
}

// ---- h = h + relu(agg*scale + shift); also write hb (bf16)
__global__ void bn_apply(float* __restrict__ h, u16* __restrict__ hb,
                         const float* __restrict__ agg,
                         const float* __restrict__ bn, int N) {
    int idx = blockIdx.x * 256 + threadIdx.x;   // float4 index
    if (idx >= N * 32) return;
    int c4 = idx & 31;
    float4 a  = ((const float4*)agg)[idx];
    float4 sc = *(const float4*)(bn + 256 + c4 * 4);
    float4 sh = *(const float4*)(bn + 384 + c4 * 4);
    float4 hv = ((float4*)h)[idx];
    hv.x += fmaxf(a.x * sc.x + sh.x, 0.f);
    hv.y += fmaxf(a.y * sc.y + sh.y, 0.f);
    hv.z += fmaxf(a.z * sc.z + sh.z, 0.f);
    hv.w += fmaxf(a.w * sc.w + sh.w, 0.f);
    ((float4*)h)[idx] = hv;
    ushort4 o; o.x = f2b(hv.x); o.y = f2b(hv.y); o.z = f2b(hv.z); o.w = f2b(hv.w);
    ((ushort4*)hb)[idx] = o;
}

// ---- per-graph sums (graph_ids sorted; flush-on-change)
__global__ void readout_kernel(const float* __restrict__ h, const int* __restrict__ gids,
                               float* __restrict__ hg, float* __restrict__ cnts, int N) {
    int c = threadIdx.x;
    int r0 = blockIdx.x * 250;
    if (r0 >= N) return;
    int r1 = min(r0 + 250, N);
    int cur = gids[r0];
    float acc = 0.f, cnt = 0.f;
    for (int r = r0; r < r1; r++) {
        int g = gids[r];
        if (g != cur) {
            atomicAdd(&hg[(size_t)cur * 128 + c], acc);
            if (c == 0) atomicAdd(&cnts[cur], cnt);
            acc = 0.f; cnt = 0.f; cur = g;
        }
        acc += h[(size_t)r * 128 + c];
        cnt += 1.f;
    }
    atomicAdd(&hg[(size_t)cur * 128 + c], acc);
    if (c == 0) atomicAdd(&cnts[cur], cnt);
}

// ---- MLP readout
__global__ void mlp_kernel(const float* __restrict__ hg, const float* __restrict__ cnts,
                           const float* __restrict__ W1, const float* __restrict__ b1,
                           const float* __restrict__ W2, const float* __restrict__ b2,
                           const float* __restrict__ W3, const float* __restrict__ b3,
                           float* __restrict__ out) {
    __shared__ float v[128], y1[64], y2[32];
    int g = blockIdx.x, t = threadIdx.x;
    float inv = 1.0f / cnts[g];
    v[t] = hg[(size_t)g * 128 + t] * inv;
    __syncthreads();
    if (t < 64) {
        float a = b1[t];
        for (int k = 0; k < 128; k++) a += v[k] * W1[k * 64 + t];
        y1[t] = fmaxf(a, 0.f);
    }
    __syncthreads();
    if (t < 32) {
        float a = b2[t];
        for (int k = 0; k < 64; k++) a += y1[k] * W2[k * 32 + t];
        y2[t] = fmaxf(a, 0.f);
    }
    __syncthreads();
    if (t < 10) {
        float a = b3[t];
        for (int k = 0; k < 32; k++) a += y2[k] * W3[k * 10 + t];
        out[g * 10 + t] = a;
    }
}

extern "C" void kernel_launch(void* const* d_in, const int* in_sizes, int n_in,
                              void* d_out, int out_size, void* d_ws, size_t ws_size,
                              hipStream_t stream) {
    const float* x      = (const float*)d_in[0];
    const float* emb_W  = (const float*)d_in[1];
    const float* emb_b  = (const float*)d_in[2];
    const float* fc_W   = (const float*)d_in[3];
    const float* fc_b   = (const float*)d_in[4];
    const float* mu     = (const float*)d_in[5];
    const float* isig   = (const float*)d_in[6];
    const float* gamma  = (const float*)d_in[7];
    const float* beta   = (const float*)d_in[8];
    const float* ppW    = (const float*)d_in[9];
    const float* ppb    = (const float*)d_in[10];
    const float* W1     = (const float*)d_in[11];
    const float* b1     = (const float*)d_in[12];
    const float* W2     = (const float*)d_in[13];
    const float* b2     = (const float*)d_in[14];
    const float* W3     = (const float*)d_in[15];
    const float* b3     = (const float*)d_in[16];
    const int*   src    = (const int*)d_in[17];
    const int*   dst    = (const int*)d_in[18];
    const int*   gids   = (const int*)d_in[19];

    const int N = in_sizes[0] / 128;
    const int E = in_sizes[17];
    const int L = in_sizes[8] / 128;
    const int G = out_size / 10;
    float* out = (float*)d_out;

    char* wp = (char*)d_ws;
    auto alloc = [&](size_t bytes) {
        char* p = wp;
        wp += (bytes + 255) & ~(size_t)255;
        return (void*)p;
    };
    float* h      = (float*)alloc((size_t)N * 128 * 4);
    u16*   hb     = (u16*)alloc((size_t)N * 128 * 2);
    u16*   t      = (u16*)alloc((size_t)N * 384 * 2);      // also reused as xb before loop
    float* agg    = (float*)alloc((size_t)N * 128 * 4);
    float* pgw    = (float*)alloc((size_t)L * E * 4 * 4);
    int*   psrc   = (int*)alloc((size_t)E * 4);
    int*   pdst   = (int*)alloc((size_t)E * 4);
    float* sk     = (float*)alloc((size_t)N * 4 * 4);
    int*   cnt    = (int*)alloc((size_t)N * 4);
    int*   rs     = (int*)alloc((size_t)(N + 1) * 4);
    int*   cursor = (int*)alloc((size_t)N * 4);
    int*   bsum   = (int*)alloc(256 * 4);
    int*   boff   = (int*)alloc(256 * 4);
    u16*   wembt  = (u16*)alloc((size_t)128 * 128 * 2);
    u16*   wfct   = (u16*)alloc((size_t)L * 128 * 384 * 2);
    float* bn     = (float*)alloc(512 * 4);
    float* hg     = (float*)alloc((size_t)G * 128 * 4);
    float* cnts   = (float*)alloc((size_t)G * 4);
    u16*   xb     = (u16*)t;   // overlay: xb only needed before first agg

    hipMemsetAsync(cnt, 0, (size_t)N * 4, stream);
    hipMemsetAsync(cursor, 0, (size_t)N * 4, stream);
    hipMemsetAsync(hg, 0, (size_t)G * 128 * 4, stream);
    hipMemsetAsync(cnts, 0, (size_t)G * 4, stream);

    // conversions + weight prep
    cvt_bf16<<<(N * 32 + 255) / 256, 256, 0, stream>>>(x, xb, N * 32);
    prep_embW<<<(128 * 128 + 255) / 256, 256, 0, stream>>>(emb_W, wembt);
    prep_fcW<<<(L * 128 * 384 + 255) / 256, 256, 0, stream>>>(fc_W, wfct, L * 128 * 384);

    // CSR build
    const int nb = (N + 255) / 256;
    hist_kernel<<<(E + 255) / 256, 256, 0, stream>>>(dst, cnt, E);
    scan_partial<<<nb, 256, 0, stream>>>(cnt, bsum, N);
    scan_bsums<<<1, 256, 0, stream>>>(bsum, boff, nb);
    scan_final<<<nb, 256, 0, stream>>>(cnt, boff, rs, N);
    scatter_kernel<<<(E + 255) / 256, 256, 0, stream>>>(src, dst, rs, cursor, psrc, pdst, E);
    gw_kernel<<<(E + 255) / 256, 256, 0, stream>>>(psrc, pdst, cnt, ppW, ppb, mu, isig, pgw, E, L);

    // node embedding: h = x @ emb_W + emb_b (writes h fp32 + hb bf16)
    const int gblocks = (N + 127) / 128;
    gemm_mfma<<<gblocks, 256, 0, stream>>>(xb, wembt, N, 128, emb_b, nullptr, h, hb, 0);

    for (int l = 0; l < L; l++) {
        agg_kernel<<<(N + 3) / 4, 256, 0, stream>>>(hb, pgw + (size_t)l * E * 4, psrc, rs, t, sk, N);
        gemm_mfma<<<gblocks, 256, 0, stream>>>(t, wfct + (size_t)l * 128 * 384, N, 384,
                                               fc_b + (size_t)l * 384, sk, agg, nullptr, 1);
        hipMemsetAsync(bn, 0, 256 * 4, stream);
        bn_stats<<<(N + 63) / 64, 128, 0, stream>>>(agg, bn, N);
        bn_finalize<<<1, 128, 0, stream>>>(bn, gamma + l * 128, beta + l * 128, N);
        bn_apply<<<(N * 32 + 255) / 256, 256, 0, stream>>>(h, hb, agg, bn, N);
    }

    readout_kernel<<<(N + 249) / 250, 128, 0, stream>>>(h, gids, hg, cnts, N);
    mlp_kernel<<<G, 128, 0, stream>>>(hg, cnts, W1, b1, W2, b2, W3, b3, out);
}

// Round 4
// 509.219 us; speedup vs baseline: 4.4883x; 1.4112x over previous
//
#include <hip/hip_runtime.h>

// ---------------------------------------------------------------------------
// MoNet GNN: N=50000, E=800000, H=128, K=3, L=4, pdim=2, G=50
// Round 4: parallel readout, BN-stats fused into fc-GEMM epilogue,
//          bn_finalize inlined into bn_apply, agg uniform-load + unroll 8.
// ---------------------------------------------------------------------------

typedef unsigned short u16;
typedef unsigned int   u32;
typedef __attribute__((ext_vector_type(8))) short bf16x8;
typedef __attribute__((ext_vector_type(4))) float f32x4;

__device__ __forceinline__ u16 f2b(float f) {
    union { float f; u32 u; } v; v.f = f;
    u32 u = v.u;
    u32 r = (u + 0x7fffu + ((u >> 16) & 1u)) >> 16;   // RNE
    return (u16)r;
}
__device__ __forceinline__ float blo(u32 h) {
    union { u32 u; float f; } v; v.u = h << 16; return v.f;
}
__device__ __forceinline__ float bhi(u32 h) {
    union { u32 u; float f; } v; v.u = h & 0xffff0000u; return v.f;
}

// ---- fp32 -> bf16 conversion (x4 per thread)
__global__ void cvt_bf16(const float* __restrict__ in, u16* __restrict__ out, int n4) {
    int i = blockIdx.x * 256 + threadIdx.x;
    if (i >= n4) return;
    float4 v = ((const float4*)in)[i];
    ushort4 o; o.x = f2b(v.x); o.y = f2b(v.y); o.z = f2b(v.z); o.w = f2b(v.w);
    ((ushort4*)out)[i] = o;
}

// ---- prep emb_W^T in bf16: Bt[n][k] = emb_W[k*128+n]
__global__ void prep_embW(const float* __restrict__ W, u16* __restrict__ Bt) {
    int idx = blockIdx.x * 256 + threadIdx.x;   // 16384
    int n = idx >> 7, k = idx & 127;
    Bt[idx] = f2b(W[k * 128 + n]);
}

// ---- prep fc weights: Bp[l][n][kc*128+r] = fcW[l][r][kc*128+n]  (bf16, B^T)
__global__ void prep_fcW(const float* __restrict__ W, u16* __restrict__ Bp, int total) {
    int idx = blockIdx.x * 256 + threadIdx.x;   // L*128*384
    if (idx >= total) return;
    int kk = idx % 384;
    int rest = idx / 384;
    int n = rest & 127;
    int l = rest >> 7;
    int kc = kk >> 7, r = kk & 127;
    Bp[idx] = f2b(W[((size_t)(l * 128 + r)) * 384 + kc * 128 + n]);
}

// ---- in-degree histogram
__global__ void hist_kernel(const int* __restrict__ dst, int* __restrict__ cnt, int E) {
    int e = blockIdx.x * 256 + threadIdx.x;
    if (e < E) atomicAdd(&cnt[dst[e]], 1);
}

// ---- 3-phase exclusive scan of cnt[N] -> rs[N+1]
__global__ void scan_partial(const int* __restrict__ cnt, int* __restrict__ bsum, int N) {
    __shared__ int buf[256];
    int t = threadIdx.x, base = blockIdx.x * 256;
    buf[t] = (base + t < N) ? cnt[base + t] : 0;
    __syncthreads();
    for (int off = 128; off > 0; off >>= 1) {
        if (t < off) buf[t] += buf[t + off];
        __syncthreads();
    }
    if (t == 0) bsum[blockIdx.x] = buf[0];
}
__global__ void scan_bsums(const int* __restrict__ bsum, int* __restrict__ boff, int nb) {
    __shared__ int buf[256];
    int t = threadIdx.x;
    int v = (t < nb) ? bsum[t] : 0;
    buf[t] = v;
    __syncthreads();
    for (int off = 1; off < 256; off <<= 1) {
        int x = (t >= off) ? buf[t - off] : 0;
        __syncthreads();
        buf[t] += x;
        __syncthreads();
    }
    if (t < nb) boff[t] = buf[t] - v;   // exclusive
}
__global__ void scan_final(const int* __restrict__ cnt, const int* __restrict__ boff,
                           int* __restrict__ rs, int N) {
    __shared__ int buf[256];
    int t = threadIdx.x, base = blockIdx.x * 256;
    int v = (base + t < N) ? cnt[base + t] : 0;
    buf[t] = v;
    __syncthreads();
    for (int off = 1; off < 256; off <<= 1) {
        int x = (t >= off) ? buf[t - off] : 0;
        __syncthreads();
        buf[t] += x;
        __syncthreads();
    }
    if (base + t < N) rs[base + t + 1] = boff[blockIdx.x] + buf[t];
    if (base == 0 && t == 0) rs[0] = 0;
}

// ---- scatter edges into dst-sorted order
__global__ void scatter_kernel(const int* __restrict__ src, const int* __restrict__ dst,
                               const int* __restrict__ rs, int* __restrict__ cursor,
                               int* __restrict__ psrc, int* __restrict__ pdst, int E) {
    int e = blockIdx.x * 256 + threadIdx.x;
    if (e >= E) return;
    int d = dst[e];
    int pos = rs[d] + atomicAdd(&cursor[d], 1);
    psrc[pos] = src[e];
    pdst[pos] = d;
}

// ---- Gaussian weights in permuted order, all L layers, padded float4
__global__ void gw_kernel(const int* __restrict__ psrc, const int* __restrict__ pdst,
                          const int* __restrict__ cnt,
                          const float* __restrict__ ppW, const float* __restrict__ ppb,
                          const float* __restrict__ mu, const float* __restrict__ isig,
                          float* __restrict__ pgw, int E, int L) {
    int p = blockIdx.x * 256 + threadIdx.x;
    if (p >= E) return;
    float ps0 = rsqrtf((float)cnt[psrc[p]] + 1.0f);
    float ps1 = rsqrtf((float)cnt[pdst[p]] + 1.0f);
    for (int l = 0; l < L; l++) {
        float p0 = tanhf(ps0 * ppW[l * 4 + 0] + ps1 * ppW[l * 4 + 2] + ppb[l * 2 + 0]);
        float p1 = tanhf(ps0 * ppW[l * 4 + 1] + ps1 * ppW[l * 4 + 3] + ppb[l * 2 + 1]);
        float4 o;
        float* ov = (float*)&o;
#pragma unroll
        for (int k = 0; k < 3; k++) {
            float d0 = (p0 - mu[(l * 3 + k) * 2 + 0]) * isig[(l * 3 + k) * 2 + 0];
            float d1 = (p1 - mu[(l * 3 + k) * 2 + 1]) * isig[(l * 3 + k) * 2 + 1];
            ov[k] = expf(-0.5f * (d0 * d0 + d1 * d1));
        }
        o.w = 0.f;
        ((float4*)pgw)[(size_t)l * E + p] = o;
    }
}

// ---- per-node aggregation: one wave per node, 2 channels per lane, unroll 8.
__global__ __launch_bounds__(256) void agg_kernel(const u16* __restrict__ hb,
                                                  const float* __restrict__ pgw,
                                                  const int* __restrict__ psrc,
                                                  const int* __restrict__ rs,
                                                  u16* __restrict__ t,
                                                  float* __restrict__ sk, int N) {
    int nid = blockIdx.x * 4 + (threadIdx.x >> 6);
    if (nid >= N) return;
    int lane = threadIdx.x & 63;
    // wave-uniform bounds -> uniform (scalar-cached) psrc/gw loads
    int p0 = __builtin_amdgcn_readfirstlane(rs[nid]);
    int p1 = __builtin_amdgcn_readfirstlane(rs[nid + 1]);
    float a00 = 0.f, a01 = 0.f, a10 = 0.f, a11 = 0.f, a20 = 0.f, a21 = 0.f;
    float gs0 = 0.f, gs1 = 0.f, gs2 = 0.f;
    const float4* pg4 = (const float4*)pgw;
    int p = p0;
    for (; p + 8 <= p1; p += 8) {
        int4 sa = *(const int4*)(psrc + p);
        int4 sb = *(const int4*)(psrc + p + 4);
        int sv[8] = {sa.x, sa.y, sa.z, sa.w, sb.x, sb.y, sb.z, sb.w};
        u32 hv[8];
        float4 gv[8];
#pragma unroll
        for (int j = 0; j < 8; j++) hv[j] = *(const u32*)(hb + (size_t)sv[j] * 128 + lane * 2);
#pragma unroll
        for (int j = 0; j < 8; j++) gv[j] = pg4[p + j];
#pragma unroll
        for (int j = 0; j < 8; j++) {
            float fl = blo(hv[j]), fh = bhi(hv[j]);
            a00 += gv[j].x * fl; a01 += gv[j].x * fh;
            a10 += gv[j].y * fl; a11 += gv[j].y * fh;
            a20 += gv[j].z * fl; a21 += gv[j].z * fh;
            gs0 += gv[j].x; gs1 += gv[j].y; gs2 += gv[j].z;
        }
    }
    if (p + 4 <= p1) {
        int4 sa = *(const int4*)(psrc + p);
        int sv[4] = {sa.x, sa.y, sa.z, sa.w};
        u32 hv[4];
        float4 gv[4];
#pragma unroll
        for (int j = 0; j < 4; j++) hv[j] = *(const u32*)(hb + (size_t)sv[j] * 128 + lane * 2);
#pragma unroll
        for (int j = 0; j < 4; j++) gv[j] = pg4[p + j];
#pragma unroll
        for (int j = 0; j < 4; j++) {
            float fl = blo(hv[j]), fh = bhi(hv[j]);
            a00 += gv[j].x * fl; a01 += gv[j].x * fh;
            a10 += gv[j].y * fl; a11 += gv[j].y * fh;
            a20 += gv[j].z * fl; a21 += gv[j].z * fh;
            gs0 += gv[j].x; gs1 += gv[j].y; gs2 += gv[j].z;
        }
        p += 4;
    }
    for (; p < p1; p++) {
        int s0 = psrc[p];
        float4 g0 = pg4[p];
        u32 h0 = *(const u32*)(hb + (size_t)s0 * 128 + lane * 2);
        float fl = blo(h0), fh = bhi(h0);
        a00 += g0.x * fl; a01 += g0.x * fh;
        a10 += g0.y * fl; a11 += g0.y * fh;
        a20 += g0.z * fl; a21 += g0.z * fh;
        gs0 += g0.x; gs1 += g0.y; gs2 += g0.z;
    }
    size_t base = (size_t)nid * 384 + lane * 2;
    *(u32*)(t + base)       = (u32)f2b(a00) | ((u32)f2b(a01) << 16);
    *(u32*)(t + base + 128) = (u32)f2b(a10) | ((u32)f2b(a11) << 16);
    *(u32*)(t + base + 256) = (u32)f2b(a20) | ((u32)f2b(a21) << 16);
    if (lane == 0) {
        sk[nid * 4 + 0] = gs0;
        sk[nid * 4 + 1] = gs1;
        sk[nid * 4 + 2] = gs2;
        sk[nid * 4 + 3] = 0.f;
    }
}

// ---- bf16 MFMA GEMM: out[M,128] = A[M,KD] @ Bt[128,KD]^T (+ epilogue)
//   mode 0 (embed): v = acc + bias[col]; h=v; hb=bf16(v)
//   mode 1 (fc):    v = acc + sum_k sk[row,k]*bias[k*128+col]; agg=v;
//                   + per-channel sum/sumsq reduced into bnred[0:256] (atomics)
__global__ __launch_bounds__(256) void gemm_mfma(const u16* __restrict__ A,
                                                 const u16* __restrict__ Bt,
                                                 int M, int KD,
                                                 const float* __restrict__ bias,
                                                 const float* __restrict__ sk,
                                                 float* __restrict__ outF,
                                                 u16* __restrict__ outB,
                                                 int mode,
                                                 float* __restrict__ bnred) {
    __shared__ u16 As[128 * 64];
    __shared__ u16 Bs[128 * 64];
    const int m0 = blockIdx.x * 128;
    const int tid = threadIdx.x;
    const int lane = tid & 63;
    const int w = tid >> 6;
    const int wr = w >> 1, wc = w & 1;

    f32x4 acc[4][4];
#pragma unroll
    for (int m = 0; m < 4; m++)
#pragma unroll
        for (int n = 0; n < 4; n++) acc[m][n] = (f32x4){0.f, 0.f, 0.f, 0.f};

    for (int k0 = 0; k0 < KD; k0 += 64) {
        __syncthreads();
#pragma unroll
        for (int i = 0; i < 4; i++) {
            int idx = tid + i * 256;
            int r = idx >> 3, g = idx & 7;
            int gs = g ^ (r & 7);
            uint4 av = make_uint4(0, 0, 0, 0);
            if (m0 + r < M) av = *(const uint4*)(A + (size_t)(m0 + r) * KD + k0 + g * 8);
            *(uint4*)(As + r * 64 + gs * 8) = av;
            uint4 bv = *(const uint4*)(Bt + (size_t)r * KD + k0 + g * 8);
            *(uint4*)(Bs + r * 64 + gs * 8) = bv;
        }
        __syncthreads();
#pragma unroll
        for (int kk = 0; kk < 2; kk++) {
            bf16x8 af[4], bfr[4];
#pragma unroll
            for (int m = 0; m < 4; m++) {
                int r = wr * 64 + m * 16 + (lane & 15);
                int g = (kk * 4 + (lane >> 4)) ^ (r & 7);
                af[m] = *(const bf16x8*)(As + r * 64 + g * 8);
            }
#pragma unroll
            for (int n = 0; n < 4; n++) {
                int r = wc * 64 + n * 16 + (lane & 15);
                int g = (kk * 4 + (lane >> 4)) ^ (r & 7);
                bfr[n] = *(const bf16x8*)(Bs + r * 64 + g * 8);
            }
#pragma unroll
            for (int m = 0; m < 4; m++)
#pragma unroll
                for (int n = 0; n < 4; n++)
                    acc[m][n] = __builtin_amdgcn_mfma_f32_16x16x32_bf16(af[m], bfr[n], acc[m][n], 0, 0, 0);
        }
    }

    // epilogue: C/D layout col=lane&15 (+16*n+64*wc), row=(lane>>4)*4+j (+16*m+64*wr)
    if (mode == 0) {
#pragma unroll
        for (int n = 0; n < 4; n++) {
            int col = wc * 64 + n * 16 + (lane & 15);
            float bv = bias[col];
#pragma unroll
            for (int m = 0; m < 4; m++) {
#pragma unroll
                for (int j = 0; j < 4; j++) {
                    int row = m0 + wr * 64 + m * 16 + (lane >> 4) * 4 + j;
                    if (row < M) {
                        float v = acc[m][n][j] + bv;
                        outF[(size_t)row * 128 + col] = v;
                        outB[(size_t)row * 128 + col] = f2b(v);
                    }
                }
            }
        }
    } else {
        float colsum[4] = {0.f, 0.f, 0.f, 0.f};
        float colsq[4]  = {0.f, 0.f, 0.f, 0.f};
#pragma unroll
        for (int n = 0; n < 4; n++) {
            int col = wc * 64 + n * 16 + (lane & 15);
            float b0 = bias[col], b1 = bias[128 + col], b2 = bias[256 + col];
#pragma unroll
            for (int m = 0; m < 4; m++) {
#pragma unroll
                for (int j = 0; j < 4; j++) {
                    int row = m0 + wr * 64 + m * 16 + (lane >> 4) * 4 + j;
                    if (row < M) {
                        float4 skv = *(const float4*)(sk + row * 4);
                        float v = acc[m][n][j] + skv.x * b0 + skv.y * b1 + skv.z * b2;
                        outF[(size_t)row * 128 + col] = v;
                        colsum[n] += v;
                        colsq[n]  += v * v;
                    }
                }
            }
        }
        // reduce per-channel sums: shfl over lane>>4 groups -> LDS -> global
        __syncthreads();                 // all LDS reads of As/Bs done
        float* red = (float*)As;         // 256 floats: [0:128] sum, [128:256] sq
        if (tid < 256) red[tid] = 0.f;
        __syncthreads();
#pragma unroll
        for (int n = 0; n < 4; n++) {
            float s = colsum[n], q = colsq[n];
            s += __shfl_xor(s, 16); s += __shfl_xor(s, 32);
            q += __shfl_xor(q, 16); q += __shfl_xor(q, 32);
            if (lane < 16) {
                int col = wc * 64 + n * 16 + lane;
                atomicAdd(&red[col], s);
                atomicAdd(&red[128 + col], q);
            }
        }
        __syncthreads();
        if (tid < 256) atomicAdd(&bnred[tid], red[tid]);
    }
}

// ---- h = h + relu((agg-mean)*rstd*gamma + beta); scale/shift from raw sums
__global__ void bn_apply(float* __restrict__ h, u16* __restrict__ hb,
                         const float* __restrict__ agg,
                         const float* __restrict__ bnred,
                         const float* __restrict__ gamma, const float* __restrict__ beta,
                         float invN, int N) {
    int idx = blockIdx.x * 256 + threadIdx.x;   // float4 index
    if (idx >= N * 32) return;
    int c4 = idx & 31;
    float4 s  = *(const float4*)(bnred + c4 * 4);
    float4 q  = *(const float4*)(bnred + 128 + c4 * 4);
    float4 ga = *(const float4*)(gamma + c4 * 4);
    float4 be = *(const float4*)(beta + c4 * 4);
    float4 sc, sh;
    {
        float m, v2;
        m = s.x * invN; v2 = q.x * invN - m * m; sc.x = ga.x * rsqrtf(v2 + 1e-5f); sh.x = be.x - m * sc.x;
        m = s.y * invN; v2 = q.y * invN - m * m; sc.y = ga.y * rsqrtf(v2 + 1e-5f); sh.y = be.y - m * sc.y;
        m = s.z * invN; v2 = q.z * invN - m * m; sc.z = ga.z * rsqrtf(v2 + 1e-5f); sh.z = be.z - m * sc.z;
        m = s.w * invN; v2 = q.w * invN - m * m; sc.w = ga.w * rsqrtf(v2 + 1e-5f); sh.w = be.w - m * sc.w;
    }
    float4 a  = ((const float4*)agg)[idx];
    float4 hv = ((float4*)h)[idx];
    hv.x += fmaxf(a.x * sc.x + sh.x, 0.f);
    hv.y += fmaxf(a.y * sc.y + sh.y, 0.f);
    hv.z += fmaxf(a.z * sc.z + sh.z, 0.f);
    hv.w += fmaxf(a.w * sc.w + sh.w, 0.f);
    ((float4*)h)[idx] = hv;
    ushort4 o; o.x = f2b(hv.x); o.y = f2b(hv.y); o.z = f2b(hv.z); o.w = f2b(hv.w);
    ((ushort4*)hb)[idx] = o;
}

// ---- per-graph sums: 25 rows per block (graph_ids sorted; flush-on-change)
__global__ void readout_kernel(const float* __restrict__ h, const int* __restrict__ gids,
                               float* __restrict__ hg, float* __restrict__ cnts, int N) {
    int c = threadIdx.x;
    int r0 = blockIdx.x * 25;
    if (r0 >= N) return;
    int r1 = min(r0 + 25, N);
    int cur = gids[r0];
    float acc = 0.f, cnt = 0.f;
    for (int r = r0; r < r1; r++) {
        int g = gids[r];
        if (g != cur) {
            atomicAdd(&hg[(size_t)cur * 128 + c], acc);
            if (c == 0) atomicAdd(&cnts[cur], cnt);
            acc = 0.f; cnt = 0.f; cur = g;
        }
        acc += h[(size_t)r * 128 + c];
        cnt += 1.f;
    }
    atomicAdd(&hg[(size_t)cur * 128 + c], acc);
    if (c == 0) atomicAdd(&cnts[cur], cnt);
}

// ---- MLP readout
__global__ void mlp_kernel(const float* __restrict__ hg, const float* __restrict__ cnts,
                           const float* __restrict__ W1, const float* __restrict__ b1,
                           const float* __restrict__ W2, const float* __restrict__ b2,
                           const float* __restrict__ W3, const float* __restrict__ b3,
                           float* __restrict__ out) {
    __shared__ float v[128], y1[64], y2[32];
    int g = blockIdx.x, t = threadIdx.x;
    float inv = 1.0f / cnts[g];
    v[t] = hg[(size_t)g * 128 + t] * inv;
    __syncthreads();
    if (t < 64) {
        float a = b1[t];
        for (int k = 0; k < 128; k++) a += v[k] * W1[k * 64 + t];
        y1[t] = fmaxf(a, 0.f);
    }
    __syncthreads();
    if (t < 32) {
        float a = b2[t];
        for (int k = 0; k < 64; k++) a += y1[k] * W2[k * 32 + t];
        y2[t] = fmaxf(a, 0.f);
    }
    __syncthreads();
    if (t < 10) {
        float a = b3[t];
        for (int k = 0; k < 32; k++) a += y2[k] * W3[k * 10 + t];
        out[g * 10 + t] = a;
    }
}

extern "C" void kernel_launch(void* const* d_in, const int* in_sizes, int n_in,
                              void* d_out, int out_size, void* d_ws, size_t ws_size,
                              hipStream_t stream) {
    const float* x      = (const float*)d_in[0];
    const float* emb_W  = (const float*)d_in[1];
    const float* emb_b  = (const float*)d_in[2];
    const float* fc_W   = (const float*)d_in[3];
    const float* fc_b   = (const float*)d_in[4];
    const float* mu     = (const float*)d_in[5];
    const float* isig   = (const float*)d_in[6];
    const float* gamma  = (const float*)d_in[7];
    const float* beta   = (const float*)d_in[8];
    const float* ppW    = (const float*)d_in[9];
    const float* ppb    = (const float*)d_in[10];
    const float* W1     = (const float*)d_in[11];
    const float* b1     = (const float*)d_in[12];
    const float* W2     = (const float*)d_in[13];
    const float* b2     = (const float*)d_in[14];
    const float* W3     = (const float*)d_in[15];
    const float* b3     = (const float*)d_in[16];
    const int*   src    = (const int*)d_in[17];
    const int*   dst    = (const int*)d_in[18];
    const int*   gids   = (const int*)d_in[19];

    const int N = in_sizes[0] / 128;
    const int E = in_sizes[17];
    const int L = in_sizes[8] / 128;
    const int G = out_size / 10;
    float* out = (float*)d_out;

    char* wp = (char*)d_ws;
    auto alloc = [&](size_t bytes) {
        char* p = wp;
        wp += (bytes + 255) & ~(size_t)255;
        return (void*)p;
    };
    float* h      = (float*)alloc((size_t)N * 128 * 4);
    u16*   hb     = (u16*)alloc((size_t)N * 128 * 2);
    u16*   t      = (u16*)alloc((size_t)N * 384 * 2);
    float* agg    = (float*)alloc((size_t)N * 128 * 4);
    float* pgw    = (float*)alloc((size_t)L * E * 4 * 4);
    int*   psrc   = (int*)alloc((size_t)E * 4);
    int*   pdst   = (int*)alloc((size_t)E * 4);
    float* sk     = (float*)alloc((size_t)N * 4 * 4);
    int*   cnt    = (int*)alloc((size_t)N * 4);
    int*   rs     = (int*)alloc((size_t)(N + 1) * 4);
    int*   cursor = (int*)alloc((size_t)N * 4);
    int*   bsum   = (int*)alloc(256 * 4);
    int*   boff   = (int*)alloc(256 * 4);
    u16*   wembt  = (u16*)alloc((size_t)128 * 128 * 2);
    u16*   wfct   = (u16*)alloc((size_t)L * 128 * 384 * 2);
    float* bnAll  = (float*)alloc((size_t)L * 256 * 4);
    float* hg     = (float*)alloc((size_t)G * 128 * 4);
    float* cnts   = (float*)alloc((size_t)G * 4);
    u16*   xb     = (u16*)t;   // overlay: xb only needed before first agg

    hipMemsetAsync(cnt, 0, (size_t)N * 4, stream);
    hipMemsetAsync(cursor, 0, (size_t)N * 4, stream);
    hipMemsetAsync(hg, 0, (size_t)G * 128 * 4, stream);
    hipMemsetAsync(cnts, 0, (size_t)G * 4, stream);
    hipMemsetAsync(bnAll, 0, (size_t)L * 256 * 4, stream);

    // conversions + weight prep
    cvt_bf16<<<(N * 32 + 255) / 256, 256, 0, stream>>>(x, xb, N * 32);
    prep_embW<<<(128 * 128 + 255) / 256, 256, 0, stream>>>(emb_W, wembt);
    prep_fcW<<<(L * 128 * 384 + 255) / 256, 256, 0, stream>>>(fc_W, wfct, L * 128 * 384);

    // CSR build
    const int nb = (N + 255) / 256;
    hist_kernel<<<(E + 255) / 256, 256, 0, stream>>>(dst, cnt, E);
    scan_partial<<<nb, 256, 0, stream>>>(cnt, bsum, N);
    scan_bsums<<<1, 256, 0, stream>>>(bsum, boff, nb);
    scan_final<<<nb, 256, 0, stream>>>(cnt, boff, rs, N);
    scatter_kernel<<<(E + 255) / 256, 256, 0, stream>>>(src, dst, rs, cursor, psrc, pdst, E);
    gw_kernel<<<(E + 255) / 256, 256, 0, stream>>>(psrc, pdst, cnt, ppW, ppb, mu, isig, pgw, E, L);

    // node embedding
    const int gblocks = (N + 127) / 128;
    gemm_mfma<<<gblocks, 256, 0, stream>>>(xb, wembt, N, 128, emb_b, nullptr, h, hb, 0, nullptr);

    const float invN = 1.0f / (float)N;
    for (int l = 0; l < L; l++) {
        agg_kernel<<<(N + 3) / 4, 256, 0, stream>>>(hb, pgw + (size_t)l * E * 4, psrc, rs, t, sk, N);
        gemm_mfma<<<gblocks, 256, 0, stream>>>(t, wfct + (size_t)l * 128 * 384, N, 384,
                                               fc_b + (size_t)l * 384, sk, agg, nullptr, 1,
                                               bnAll + (size_t)l * 256);
        bn_apply<<<(N * 32 + 255) / 256, 256, 0, stream>>>(h, hb, agg, bnAll + (size_t)l * 256,
                                                           gamma + l * 128, beta + l * 128, invN, N);
    }

    readout_kernel<<<(N + 24) / 25, 128, 0, stream>>>(h, gids, hg, cnts, N);
    mlp_kernel<<<G, 128, 0, stream>>>(hg, cnts, W1, b1, W2, b2, W3, b3, out);
}

// Round 5
// 504.826 us; speedup vs baseline: 4.5274x; 1.0087x over previous
//
#include <hip/hip_runtime.h>

// ---------------------------------------------------------------------------
// MoNet GNN: N=50000, E=800000, H=128, K=3, L=4, pdim=2, G=50
// Round 5: scatter writes psrc only (pdst filled coalesced from CSR ranges);
//          agg processes 2 edges/iter (half-wave each, uint2 gathers, final
//          shfl_xor(32) cross-half reduce). BN fused in GEMM epilogue (R4).
// ---------------------------------------------------------------------------

typedef unsigned short u16;
typedef unsigned int   u32;
typedef __attribute__((ext_vector_type(8))) short bf16x8;
typedef __attribute__((ext_vector_type(4))) float f32x4;

__device__ __forceinline__ u16 f2b(float f) {
    union { float f; u32 u; } v; v.f = f;
    u32 u = v.u;
    u32 r = (u + 0x7fffu + ((u >> 16) & 1u)) >> 16;   // RNE
    return (u16)r;
}
__device__ __forceinline__ float blo(u32 h) {
    union { u32 u; float f; } v; v.u = h << 16; return v.f;
}
__device__ __forceinline__ float bhi(u32 h) {
    union { u32 u; float f; } v; v.u = h & 0xffff0000u; return v.f;
}

// ---- fp32 -> bf16 conversion (x4 per thread)
__global__ void cvt_bf16(const float* __restrict__ in, u16* __restrict__ out, int n4) {
    int i = blockIdx.x * 256 + threadIdx.x;
    if (i >= n4) return;
    float4 v = ((const float4*)in)[i];
    ushort4 o; o.x = f2b(v.x); o.y = f2b(v.y); o.z = f2b(v.z); o.w = f2b(v.w);
    ((ushort4*)out)[i] = o;
}

// ---- prep emb_W^T in bf16: Bt[n][k] = emb_W[k*128+n]
__global__ void prep_embW(const float* __restrict__ W, u16* __restrict__ Bt) {
    int idx = blockIdx.x * 256 + threadIdx.x;   // 16384
    int n = idx >> 7, k = idx & 127;
    Bt[idx] = f2b(W[k * 128 + n]);
}

// ---- prep fc weights: Bp[l][n][kc*128+r] = fcW[l][r][kc*128+n]  (bf16, B^T)
__global__ void prep_fcW(const float* __restrict__ W, u16* __restrict__ Bp, int total) {
    int idx = blockIdx.x * 256 + threadIdx.x;   // L*128*384
    if (idx >= total) return;
    int kk = idx % 384;
    int rest = idx / 384;
    int n = rest & 127;
    int l = rest >> 7;
    int kc = kk >> 7, r = kk & 127;
    Bp[idx] = f2b(W[((size_t)(l * 128 + r)) * 384 + kc * 128 + n]);
}

// ---- in-degree histogram
__global__ void hist_kernel(const int* __restrict__ dst, int* __restrict__ cnt, int E) {
    int e = blockIdx.x * 256 + threadIdx.x;
    if (e < E) atomicAdd(&cnt[dst[e]], 1);
}

// ---- 3-phase exclusive scan of cnt[N] -> rs[N+1]
__global__ void scan_partial(const int* __restrict__ cnt, int* __restrict__ bsum, int N) {
    __shared__ int buf[256];
    int t = threadIdx.x, base = blockIdx.x * 256;
    buf[t] = (base + t < N) ? cnt[base + t] : 0;
    __syncthreads();
    for (int off = 128; off > 0; off >>= 1) {
        if (t < off) buf[t] += buf[t + off];
        __syncthreads();
    }
    if (t == 0) bsum[blockIdx.x] = buf[0];
}
__global__ void scan_bsums(const int* __restrict__ bsum, int* __restrict__ boff, int nb) {
    __shared__ int buf[256];
    int t = threadIdx.x;
    int v = (t < nb) ? bsum[t] : 0;
    buf[t] = v;
    __syncthreads();
    for (int off = 1; off < 256; off <<= 1) {
        int x = (t >= off) ? buf[t - off] : 0;
        __syncthreads();
        buf[t] += x;
        __syncthreads();
    }
    if (t < nb) boff[t] = buf[t] - v;   // exclusive
}
__global__ void scan_final(const int* __restrict__ cnt, const int* __restrict__ boff,
                           int* __restrict__ rs, int N) {
    __shared__ int buf[256];
    int t = threadIdx.x, base = blockIdx.x * 256;
    int v = (base + t < N) ? cnt[base + t] : 0;
    buf[t] = v;
    __syncthreads();
    for (int off = 1; off < 256; off <<= 1) {
        int x = (t >= off) ? buf[t - off] : 0;
        __syncthreads();
        buf[t] += x;
        __syncthreads();
    }
    if (base + t < N) rs[base + t + 1] = boff[blockIdx.x] + buf[t];
    if (base == 0 && t == 0) rs[0] = 0;
}

// ---- scatter: ONLY psrc (one 4B random store + cursor atomic per edge)
__global__ void scatter_kernel(const int* __restrict__ src, const int* __restrict__ dst,
                               const int* __restrict__ rs, int* __restrict__ cursor,
                               int* __restrict__ psrc, int E) {
    int e = blockIdx.x * 256 + threadIdx.x;
    if (e >= E) return;
    int d = dst[e];
    int pos = rs[d] + atomicAdd(&cursor[d], 1);
    psrc[pos] = src[e];
}

// ---- fill pdst from CSR ranges (coalesced sequential writes)
__global__ void fill_pdst(const int* __restrict__ rs, int* __restrict__ pdst, int N) {
    int nid = blockIdx.x * 4 + (threadIdx.x >> 6);
    if (nid >= N) return;
    int lane = threadIdx.x & 63;
    int p0 = rs[nid], p1 = rs[nid + 1];
    for (int p = p0 + lane; p < p1; p += 64) pdst[p] = nid;
}

// ---- Gaussian weights in permuted order, all L layers, padded float4
__global__ void gw_kernel(const int* __restrict__ psrc, const int* __restrict__ pdst,
                          const int* __restrict__ cnt,
                          const float* __restrict__ ppW, const float* __restrict__ ppb,
                          const float* __restrict__ mu, const float* __restrict__ isig,
                          float* __restrict__ pgw, int E, int L) {
    int p = blockIdx.x * 256 + threadIdx.x;
    if (p >= E) return;
    float ps0 = rsqrtf((float)cnt[psrc[p]] + 1.0f);
    float ps1 = rsqrtf((float)cnt[pdst[p]] + 1.0f);
    for (int l = 0; l < L; l++) {
        float p0 = tanhf(ps0 * ppW[l * 4 + 0] + ps1 * ppW[l * 4 + 2] + ppb[l * 2 + 0]);
        float p1 = tanhf(ps0 * ppW[l * 4 + 1] + ps1 * ppW[l * 4 + 3] + ppb[l * 2 + 1]);
        float4 o;
        float* ov = (float*)&o;
#pragma unroll
        for (int k = 0; k < 3; k++) {
            float d0 = (p0 - mu[(l * 3 + k) * 2 + 0]) * isig[(l * 3 + k) * 2 + 0];
            float d1 = (p1 - mu[(l * 3 + k) * 2 + 1]) * isig[(l * 3 + k) * 2 + 1];
            ov[k] = expf(-0.5f * (d0 * d0 + d1 * d1));
        }
        o.w = 0.f;
        ((float4*)pgw)[(size_t)l * E + p] = o;
    }
}

// ---- per-node aggregation: one wave per node, 2 edges per iteration.
//      lanes 0-31 handle even edge, lanes 32-63 odd edge; each lane gathers
//      uint2 (4 bf16 channels). Final cross-half shfl_xor(32) reduce.
__global__ __launch_bounds__(256) void agg_kernel(const u16* __restrict__ hb,
                                                  const float* __restrict__ pgw,
                                                  const int* __restrict__ psrc,
                                                  const int* __restrict__ rs,
                                                  u16* __restrict__ t,
                                                  float* __restrict__ sk, int N) {
    int nid = blockIdx.x * 4 + (threadIdx.x >> 6);
    if (nid >= N) return;
    int lane = threadIdx.x & 63;
    int half = lane >> 5;          // which edge of the pair
    int cl = lane & 31;            // channel group (4 ch each)
    int p0 = __builtin_amdgcn_readfirstlane(rs[nid]);
    int p1 = __builtin_amdgcn_readfirstlane(rs[nid + 1]);
    float a0[4] = {}, a1[4] = {}, a2[4] = {};
    float gs0 = 0.f, gs1 = 0.f, gs2 = 0.f;
    const float4* pg4 = (const float4*)pgw;
    int p = p0;
    // 4 pairs (8 edges) per iteration
    for (; p + 8 <= p1; p += 8) {
        int4 sa = *(const int4*)(psrc + p);       // wave-uniform
        int4 sb = *(const int4*)(psrc + p + 4);
        int s[4] = { half ? sa.y : sa.x, half ? sa.w : sa.z,
                     half ? sb.y : sb.x, half ? sb.w : sb.z };
        uint2 hv[4];
        float4 g[4];
#pragma unroll
        for (int j = 0; j < 4; j++)
            hv[j] = *(const uint2*)(hb + (size_t)s[j] * 128 + cl * 4);
#pragma unroll
        for (int j = 0; j < 4; j++)
            g[j] = pg4[p + 2 * j + half];
#pragma unroll
        for (int j = 0; j < 4; j++) {
            float f0 = blo(hv[j].x), f1 = bhi(hv[j].x), f2 = blo(hv[j].y), f3 = bhi(hv[j].y);
            a0[0] += g[j].x * f0; a0[1] += g[j].x * f1; a0[2] += g[j].x * f2; a0[3] += g[j].x * f3;
            a1[0] += g[j].y * f0; a1[1] += g[j].y * f1; a1[2] += g[j].y * f2; a1[3] += g[j].y * f3;
            a2[0] += g[j].z * f0; a2[1] += g[j].z * f1; a2[2] += g[j].z * f2; a2[3] += g[j].z * f3;
            gs0 += g[j].x; gs1 += g[j].y; gs2 += g[j].z;
        }
    }
    // remaining pairs
    for (; p + 2 <= p1; p += 2) {
        int2 sa = *(const int2*)(psrc + p);
        int s0 = half ? sa.y : sa.x;
        uint2 hv = *(const uint2*)(hb + (size_t)s0 * 128 + cl * 4);
        float4 g = pg4[p + half];
        float f0 = blo(hv.x), f1 = bhi(hv.x), f2 = blo(hv.y), f3 = bhi(hv.y);
        a0[0] += g.x * f0; a0[1] += g.x * f1; a0[2] += g.x * f2; a0[3] += g.x * f3;
        a1[0] += g.y * f0; a1[1] += g.y * f1; a1[2] += g.y * f2; a1[3] += g.y * f3;
        a2[0] += g.z * f0; a2[1] += g.z * f1; a2[2] += g.z * f2; a2[3] += g.z * f3;
        gs0 += g.x; gs1 += g.y; gs2 += g.z;
    }
    // odd tail edge: only half 0 accumulates
    if (p < p1) {
        int s0 = psrc[p];
        uint2 hv = *(const uint2*)(hb + (size_t)s0 * 128 + cl * 4);
        float4 g = pg4[p];
        float msk = half ? 0.f : 1.f;
        float gx = g.x * msk, gy = g.y * msk, gz = g.z * msk;
        float f0 = blo(hv.x), f1 = bhi(hv.x), f2 = blo(hv.y), f3 = bhi(hv.y);
        a0[0] += gx * f0; a0[1] += gx * f1; a0[2] += gx * f2; a0[3] += gx * f3;
        a1[0] += gy * f0; a1[1] += gy * f1; a1[2] += gy * f2; a1[3] += gy * f3;
        a2[0] += gz * f0; a2[1] += gz * f1; a2[2] += gz * f2; a2[3] += gz * f3;
        gs0 += gx; gs1 += gy; gs2 += gz;
    }
    // cross-half reduce (lane l += lane l^32)
#pragma unroll
    for (int c = 0; c < 4; c++) {
        a0[c] += __shfl_xor(a0[c], 32);
        a1[c] += __shfl_xor(a1[c], 32);
        a2[c] += __shfl_xor(a2[c], 32);
    }
    gs0 += __shfl_xor(gs0, 32);
    gs1 += __shfl_xor(gs1, 32);
    gs2 += __shfl_xor(gs2, 32);
    if (half == 0) {
        size_t base = (size_t)nid * 384 + cl * 4;
        ushort4 o0, o1, o2;
        o0.x = f2b(a0[0]); o0.y = f2b(a0[1]); o0.z = f2b(a0[2]); o0.w = f2b(a0[3]);
        o1.x = f2b(a1[0]); o1.y = f2b(a1[1]); o1.z = f2b(a1[2]); o1.w = f2b(a1[3]);
        o2.x = f2b(a2[0]); o2.y = f2b(a2[1]); o2.z = f2b(a2[2]); o2.w = f2b(a2[3]);
        *(ushort4*)(t + base)       = o0;
        *(ushort4*)(t + base + 128) = o1;
        *(ushort4*)(t + base + 256) = o2;
        if (cl == 0) {
            sk[nid * 4 + 0] = gs0;
            sk[nid * 4 + 1] = gs1;
            sk[nid * 4 + 2] = gs2;
            sk[nid * 4 + 3] = 0.f;
        }
    }
}

// ---- bf16 MFMA GEMM: out[M,128] = A[M,KD] @ Bt[128,KD]^T (+ epilogue)
//   mode 0 (embed): v = acc + bias[col]; h=v; hb=bf16(v)
//   mode 1 (fc):    v = acc + sum_k sk[row,k]*bias[k*128+col]; agg=v;
//                   + per-channel sum/sumsq reduced into bnred[0:256] (atomics)
__global__ __launch_bounds__(256) void gemm_mfma(const u16* __restrict__ A,
                                                 const u16* __restrict__ Bt,
                                                 int M, int KD,
                                                 const float* __restrict__ bias,
                                                 const float* __restrict__ sk,
                                                 float* __restrict__ outF,
                                                 u16* __restrict__ outB,
                                                 int mode,
                                                 float* __restrict__ bnred) {
    __shared__ u16 As[128 * 64];
    __shared__ u16 Bs[128 * 64];
    const int m0 = blockIdx.x * 128;
    const int tid = threadIdx.x;
    const int lane = tid & 63;
    const int w = tid >> 6;
    const int wr = w >> 1, wc = w & 1;

    f32x4 acc[4][4];
#pragma unroll
    for (int m = 0; m < 4; m++)
#pragma unroll
        for (int n = 0; n < 4; n++) acc[m][n] = (f32x4){0.f, 0.f, 0.f, 0.f};

    for (int k0 = 0; k0 < KD; k0 += 64) {
        __syncthreads();
#pragma unroll
        for (int i = 0; i < 4; i++) {
            int idx = tid + i * 256;
            int r = idx >> 3, g = idx & 7;
            int gs = g ^ (r & 7);
            uint4 av = make_uint4(0, 0, 0, 0);
            if (m0 + r < M) av = *(const uint4*)(A + (size_t)(m0 + r) * KD + k0 + g * 8);
            *(uint4*)(As + r * 64 + gs * 8) = av;
            uint4 bv = *(const uint4*)(Bt + (size_t)r * KD + k0 + g * 8);
            *(uint4*)(Bs + r * 64 + gs * 8) = bv;
        }
        __syncthreads();
#pragma unroll
        for (int kk = 0; kk < 2; kk++) {
            bf16x8 af[4], bfr[4];
#pragma unroll
            for (int m = 0; m < 4; m++) {
                int r = wr * 64 + m * 16 + (lane & 15);
                int g = (kk * 4 + (lane >> 4)) ^ (r & 7);
                af[m] = *(const bf16x8*)(As + r * 64 + g * 8);
            }
#pragma unroll
            for (int n = 0; n < 4; n++) {
                int r = wc * 64 + n * 16 + (lane & 15);
                int g = (kk * 4 + (lane >> 4)) ^ (r & 7);
                bfr[n] = *(const bf16x8*)(Bs + r * 64 + g * 8);
            }
#pragma unroll
            for (int m = 0; m < 4; m++)
#pragma unroll
                for (int n = 0; n < 4; n++)
                    acc[m][n] = __builtin_amdgcn_mfma_f32_16x16x32_bf16(af[m], bfr[n], acc[m][n], 0, 0, 0);
        }
    }

    // epilogue: C/D layout col=lane&15 (+16*n+64*wc), row=(lane>>4)*4+j (+16*m+64*wr)
    if (mode == 0) {
#pragma unroll
        for (int n = 0; n < 4; n++) {
            int col = wc * 64 + n * 16 + (lane & 15);
            float bv = bias[col];
#pragma unroll
            for (int m = 0; m < 4; m++) {
#pragma unroll
                for (int j = 0; j < 4; j++) {
                    int row = m0 + wr * 64 + m * 16 + (lane >> 4) * 4 + j;
                    if (row < M) {
                        float v = acc[m][n][j] + bv;
                        outF[(size_t)row * 128 + col] = v;
                        outB[(size_t)row * 128 + col] = f2b(v);
                    }
                }
            }
        }
    } else {
        float colsum[4] = {0.f, 0.f, 0.f, 0.f};
        float colsq[4]  = {0.f, 0.f, 0.f, 0.f};
#pragma unroll
        for (int n = 0; n < 4; n++) {
            int col = wc * 64 + n * 16 + (lane & 15);
            float b0 = bias[col], b1 = bias[128 + col], b2 = bias[256 + col];
#pragma unroll
            for (int m = 0; m < 4; m++) {
#pragma unroll
                for (int j = 0; j < 4; j++) {
                    int row = m0 + wr * 64 + m * 16 + (lane >> 4) * 4 + j;
                    if (row < M) {
                        float4 skv = *(const float4*)(sk + row * 4);
                        float v = acc[m][n][j] + skv.x * b0 + skv.y * b1 + skv.z * b2;
                        outF[(size_t)row * 128 + col] = v;
                        colsum[n] += v;
                        colsq[n]  += v * v;
                    }
                }
            }
        }
        // reduce per-channel sums: shfl over row-groups -> LDS -> global
        __syncthreads();
        float* red = (float*)As;         // 256 floats: [0:128] sum, [128:256] sq
        if (tid < 256) red[tid] = 0.f;
        __syncthreads();
#pragma unroll
        for (int n = 0; n < 4; n++) {
            float s = colsum[n], q = colsq[n];
            s += __shfl_xor(s, 16); s += __shfl_xor(s, 32);
            q += __shfl_xor(q, 16); q += __shfl_xor(q, 32);
            if (lane < 16) {
                int col = wc * 64 + n * 16 + lane;
                atomicAdd(&red[col], s);
                atomicAdd(&red[128 + col], q);
            }
        }
        __syncthreads();
        if (tid < 256) atomicAdd(&bnred[tid], red[tid]);
    }
}

// ---- h = h + relu((agg-mean)*rstd*gamma + beta); scale/shift from raw sums
__global__ void bn_apply(float* __restrict__ h, u16* __restrict__ hb,
                         const float* __restrict__ agg,
                         const float* __restrict__ bnred,
                         const float* __restrict__ gamma, const float* __restrict__ beta,
                         float invN, int N) {
    int idx = blockIdx.x * 256 + threadIdx.x;   // float4 index
    if (idx >= N * 32) return;
    int c4 = idx & 31;
    float4 s  = *(const float4*)(bnred + c4 * 4);
    float4 q  = *(const float4*)(bnred + 128 + c4 * 4);
    float4 ga = *(const float4*)(gamma + c4 * 4);
    float4 be = *(const float4*)(beta + c4 * 4);
    float4 sc, sh;
    {
        float m, v2;
        m = s.x * invN; v2 = q.x * invN - m * m; sc.x = ga.x * rsqrtf(v2 + 1e-5f); sh.x = be.x - m * sc.x;
        m = s.y * invN; v2 = q.y * invN - m * m; sc.y = ga.y * rsqrtf(v2 + 1e-5f); sh.y = be.y - m * sc.y;
        m = s.z * invN; v2 = q.z * invN - m * m; sc.z = ga.z * rsqrtf(v2 + 1e-5f); sh.z = be.z - m * sc.z;
        m = s.w * invN; v2 = q.w * invN - m * m; sc.w = ga.w * rsqrtf(v2 + 1e-5f); sh.w = be.w - m * sc.w;
    }
    float4 a  = ((const float4*)agg)[idx];
    float4 hv = ((float4*)h)[idx];
    hv.x += fmaxf(a.x * sc.x + sh.x, 0.f);
    hv.y += fmaxf(a.y * sc.y + sh.y, 0.f);
    hv.z += fmaxf(a.z * sc.z + sh.z, 0.f);
    hv.w += fmaxf(a.w * sc.w + sh.w, 0.f);
    ((float4*)h)[idx] = hv;
    ushort4 o; o.x = f2b(hv.x); o.y = f2b(hv.y); o.z = f2b(hv.z); o.w = f2b(hv.w);
    ((ushort4*)hb)[idx] = o;
}

// ---- per-graph sums: 25 rows per block (graph_ids sorted; flush-on-change)
__global__ void readout_kernel(const float* __restrict__ h, const int* __restrict__ gids,
                               float* __restrict__ hg, float* __restrict__ cnts, int N) {
    int c = threadIdx.x;
    int r0 = blockIdx.x * 25;
    if (r0 >= N) return;
    int r1 = min(r0 + 25, N);
    int cur = gids[r0];
    float acc = 0.f, cnt = 0.f;
    for (int r = r0; r < r1; r++) {
        int g = gids[r];
        if (g != cur) {
            atomicAdd(&hg[(size_t)cur * 128 + c], acc);
            if (c == 0) atomicAdd(&cnts[cur], cnt);
            acc = 0.f; cnt = 0.f; cur = g;
        }
        acc += h[(size_t)r * 128 + c];
        cnt += 1.f;
    }
    atomicAdd(&hg[(size_t)cur * 128 + c], acc);
    if (c == 0) atomicAdd(&cnts[cur], cnt);
}

// ---- MLP readout
__global__ void mlp_kernel(const float* __restrict__ hg, const float* __restrict__ cnts,
                           const float* __restrict__ W1, const float* __restrict__ b1,
                           const float* __restrict__ W2, const float* __restrict__ b2,
                           const float* __restrict__ W3, const float* __restrict__ b3,
                           float* __restrict__ out) {
    __shared__ float v[128], y1[64], y2[32];
    int g = blockIdx.x, t = threadIdx.x;
    float inv = 1.0f / cnts[g];
    v[t] = hg[(size_t)g * 128 + t] * inv;
    __syncthreads();
    if (t < 64) {
        float a = b1[t];
        for (int k = 0; k < 128; k++) a += v[k] * W1[k * 64 + t];
        y1[t] = fmaxf(a, 0.f);
    }
    __syncthreads();
    if (t < 32) {
        float a = b2[t];
        for (int k = 0; k < 64; k++) a += y1[k] * W2[k * 32 + t];
        y2[t] = fmaxf(a, 0.f);
    }
    __syncthreads();
    if (t < 10) {
        float a = b3[t];
        for (int k = 0; k < 32; k++) a += y2[k] * W3[k * 10 + t];
        out[g * 10 + t] = a;
    }
}

extern "C" void kernel_launch(void* const* d_in, const int* in_sizes, int n_in,
                              void* d_out, int out_size, void* d_ws, size_t ws_size,
                              hipStream_t stream) {
    const float* x      = (const float*)d_in[0];
    const float* emb_W  = (const float*)d_in[1];
    const float* emb_b  = (const float*)d_in[2];
    const float* fc_W   = (const float*)d_in[3];
    const float* fc_b   = (const float*)d_in[4];
    const float* mu     = (const float*)d_in[5];
    const float* isig   = (const float*)d_in[6];
    const float* gamma  = (const float*)d_in[7];
    const float* beta   = (const float*)d_in[8];
    const float* ppW    = (const float*)d_in[9];
    const float* ppb    = (const float*)d_in[10];
    const float* W1     = (const float*)d_in[11];
    const float* b1     = (const float*)d_in[12];
    const float* W2     = (const float*)d_in[13];
    const float* b2     = (const float*)d_in[14];
    const float* W3     = (const float*)d_in[15];
    const float* b3     = (const float*)d_in[16];
    const int*   src    = (const int*)d_in[17];
    const int*   dst    = (const int*)d_in[18];
    const int*   gids   = (const int*)d_in[19];

    const int N = in_sizes[0] / 128;
    const int E = in_sizes[17];
    const int L = in_sizes[8] / 128;
    const int G = out_size / 10;
    float* out = (float*)d_out;

    char* wp = (char*)d_ws;
    auto alloc = [&](size_t bytes) {
        char* p = wp;
        wp += (bytes + 255) & ~(size_t)255;
        return (void*)p;
    };
    float* h      = (float*)alloc((size_t)N * 128 * 4);
    u16*   hb     = (u16*)alloc((size_t)N * 128 * 2);
    u16*   t      = (u16*)alloc((size_t)N * 384 * 2);
    float* agg    = (float*)alloc((size_t)N * 128 * 4);
    float* pgw    = (float*)alloc((size_t)L * E * 4 * 4);
    int*   psrc   = (int*)alloc((size_t)E * 4);
    int*   pdst   = (int*)alloc((size_t)E * 4);
    float* sk     = (float*)alloc((size_t)N * 4 * 4);
    int*   cnt    = (int*)alloc((size_t)N * 4);
    int*   rs     = (int*)alloc((size_t)(N + 1) * 4);
    int*   cursor = (int*)alloc((size_t)N * 4);
    int*   bsum   = (int*)alloc(256 * 4);
    int*   boff   = (int*)alloc(256 * 4);
    u16*   wembt  = (u16*)alloc((size_t)128 * 128 * 2);
    u16*   wfct   = (u16*)alloc((size_t)L * 128 * 384 * 2);
    float* bnAll  = (float*)alloc((size_t)L * 256 * 4);
    float* hg     = (float*)alloc((size_t)G * 128 * 4);
    float* cnts   = (float*)alloc((size_t)G * 4);
    u16*   xb     = (u16*)t;   // overlay: xb only needed before first agg

    hipMemsetAsync(cnt, 0, (size_t)N * 4, stream);
    hipMemsetAsync(cursor, 0, (size_t)N * 4, stream);
    hipMemsetAsync(hg, 0, (size_t)G * 128 * 4, stream);
    hipMemsetAsync(cnts, 0, (size_t)G * 4, stream);
    hipMemsetAsync(bnAll, 0, (size_t)L * 256 * 4, stream);

    // conversions + weight prep
    cvt_bf16<<<(N * 32 + 255) / 256, 256, 0, stream>>>(x, xb, N * 32);
    prep_embW<<<(128 * 128 + 255) / 256, 256, 0, stream>>>(emb_W, wembt);
    prep_fcW<<<(L * 128 * 384 + 255) / 256, 256, 0, stream>>>(fc_W, wfct, L * 128 * 384);

    // CSR build
    const int nb = (N + 255) / 256;
    hist_kernel<<<(E + 255) / 256, 256, 0, stream>>>(dst, cnt, E);
    scan_partial<<<nb, 256, 0, stream>>>(cnt, bsum, N);
    scan_bsums<<<1, 256, 0, stream>>>(bsum, boff, nb);
    scan_final<<<nb, 256, 0, stream>>>(cnt, boff, rs, N);
    scatter_kernel<<<(E + 255) / 256, 256, 0, stream>>>(src, dst, rs, cursor, psrc, E);
    fill_pdst<<<(N + 3) / 4, 256, 0, stream>>>(rs, pdst, N);
    gw_kernel<<<(E + 255) / 256, 256, 0, stream>>>(psrc, pdst, cnt, ppW, ppb, mu, isig, pgw, E, L);

    // node embedding
    const int gblocks = (N + 127) / 128;
    gemm_mfma<<<gblocks, 256, 0, stream>>>(xb, wembt, N, 128, emb_b, nullptr, h, hb, 0, nullptr);

    const float invN = 1.0f / (float)N;
    for (int l = 0; l < L; l++) {
        agg_kernel<<<(N + 3) / 4, 256, 0, stream>>>(hb, pgw + (size_t)l * E * 4, psrc, rs, t, sk, N);
        gemm_mfma<<<gblocks, 256, 0, stream>>>(t, wfct + (size_t)l * 128 * 384, N, 384,
                                               fc_b + (size_t)l * 384, sk, agg, nullptr, 1,
                                               bnAll + (size_t)l * 256);
        bn_apply<<<(N * 32 + 255) / 256, 256, 0, stream>>>(h, hb, agg, bnAll + (size_t)l * 256,
                                                           gamma + l * 128, beta + l * 128, invN, N);
    }

    readout_kernel<<<(N + 24) / 25, 128, 0, stream>>>(h, gids, hg, cnts, N);
    mlp_kernel<<<G, 128, 0, stream>>>(hg, cnts, W1, b1, W2, b2, W3, b3, out);
}

// Round 6
// 498.934 us; speedup vs baseline: 4.5809x; 1.0118x over previous
//
#include <hip/hip_runtime.h>

// ---------------------------------------------------------------------------
// MoNet GNN: N=50000, E=800000, H=128, K=3, L=4, pdim=2, G=50, npg=1000
// Round 6: graph-bucketed two-pass edge sort (no random-line scatter),
//          bf16 agg output from fc GEMM, agg 16-edge unrolled gather loop.
// Edges are intra-graph by construction (dst in [g*npg,(g+1)*npg)); pass A
// packs (src<<16)|dst_local in u32 (N<65536, npg<65536).
// ---------------------------------------------------------------------------

typedef unsigned char  u8;
typedef unsigned short u16;
typedef unsigned int   u32;
typedef __attribute__((ext_vector_type(8))) short bf16x8;
typedef __attribute__((ext_vector_type(4))) float f32x4;

__device__ __forceinline__ u16 f2b(float f) {
    union { float f; u32 u; } v; v.f = f;
    u32 u = v.u;
    u32 r = (u + 0x7fffu + ((u >> 16) & 1u)) >> 16;   // RNE
    return (u16)r;
}
__device__ __forceinline__ float blo(u32 h) {
    union { u32 u; float f; } v; v.u = h << 16; return v.f;
}
__device__ __forceinline__ float bhi(u32 h) {
    union { u32 u; float f; } v; v.u = h & 0xffff0000u; return v.f;
}

// ---- fp32 -> bf16 conversion (x4 per thread)
__global__ void cvt_bf16(const float* __restrict__ in, u16* __restrict__ out, int n4) {
    int i = blockIdx.x * 256 + threadIdx.x;
    if (i >= n4) return;
    float4 v = ((const float4*)in)[i];
    ushort4 o; o.x = f2b(v.x); o.y = f2b(v.y); o.z = f2b(v.z); o.w = f2b(v.w);
    ((ushort4*)out)[i] = o;
}

// ---- prep emb_W^T in bf16: Bt[n][k] = emb_W[k*128+n]
__global__ void prep_embW(const float* __restrict__ W, u16* __restrict__ Bt) {
    int idx = blockIdx.x * 256 + threadIdx.x;   // 16384
    int n = idx >> 7, k = idx & 127;
    Bt[idx] = f2b(W[k * 128 + n]);
}

// ---- prep fc weights: Bp[l][n][kc*128+r] = fcW[l][r][kc*128+n]  (bf16, B^T)
__global__ void prep_fcW(const float* __restrict__ W, u16* __restrict__ Bp, int total) {
    int idx = blockIdx.x * 256 + threadIdx.x;   // L*128*384
    if (idx >= total) return;
    int kk = idx % 384;
    int rest = idx / 384;
    int n = rest & 127;
    int l = rest >> 7;
    int kc = kk >> 7, r = kk & 127;
    Bp[idx] = f2b(W[((size_t)(l * 128 + r)) * 384 + kc * 128 + n]);
}

// ---- in-degree histogram
__global__ void hist_kernel(const int* __restrict__ dst, int* __restrict__ cnt, int E) {
    int e = blockIdx.x * 256 + threadIdx.x;
    if (e < E) atomicAdd(&cnt[dst[e]], 1);
}

// ---- 3-phase exclusive scan of cnt[N] -> rs[N+1]
__global__ void scan_partial(const int* __restrict__ cnt, int* __restrict__ bsum, int N) {
    __shared__ int buf[256];
    int t = threadIdx.x, base = blockIdx.x * 256;
    buf[t] = (base + t < N) ? cnt[base + t] : 0;
    __syncthreads();
    for (int off = 128; off > 0; off >>= 1) {
        if (t < off) buf[t] += buf[t + off];
        __syncthreads();
    }
    if (t == 0) bsum[blockIdx.x] = buf[0];
}
__global__ void scan_bsums(const int* __restrict__ bsum, int* __restrict__ boff, int nb) {
    __shared__ int buf[256];
    int t = threadIdx.x;
    int v = (t < nb) ? bsum[t] : 0;
    buf[t] = v;
    __syncthreads();
    for (int off = 1; off < 256; off <<= 1) {
        int x = (t >= off) ? buf[t - off] : 0;
        __syncthreads();
        buf[t] += x;
        __syncthreads();
    }
    if (t < nb) boff[t] = buf[t] - v;   // exclusive
}
__global__ void scan_final(const int* __restrict__ cnt, const int* __restrict__ boff,
                           int* __restrict__ rs, int N) {
    __shared__ int buf[256];
    int t = threadIdx.x, base = blockIdx.x * 256;
    int v = (base + t < N) ? cnt[base + t] : 0;
    buf[t] = v;
    __syncthreads();
    for (int off = 1; off < 256; off <<= 1) {
        int x = (t >= off) ? buf[t - off] : 0;
        __syncthreads();
        buf[t] += x;
        __syncthreads();
    }
    if (base + t < N) rs[base + t + 1] = boff[blockIdx.x] + buf[t];
    if (base == 0 && t == 0) rs[0] = 0;
}

// ---- Pass A: bin 4096 edges per block by graph (LDS), chunk-copy to tmp
//      tmp is graph-major: graph g region starts at rs[g*npg]
__global__ __launch_bounds__(256) void bucketA(const int* __restrict__ src,
                                               const int* __restrict__ dst,
                                               const int* __restrict__ rs,
                                               int* __restrict__ gcur,
                                               u32* __restrict__ tmp,
                                               int E, int npg, int G) {
    __shared__ u32 ebuf[4096];      // 16 KB packed edges
    __shared__ u8  gmap[4096];      // graph of each buffered slot
    __shared__ int ghist[64], gexc[64], gbase[64], lcur[64];
    const int tid = threadIdx.x;
    const int e0 = blockIdx.x * 4096;
    const int n = min(4096, E - e0);
    if (tid < 64) { ghist[tid] = 0; lcur[tid] = 0; }
    __syncthreads();
    for (int i = tid; i < n; i += 256) {
        int g = dst[e0 + i] / npg;
        atomicAdd(&ghist[g], 1);
    }
    __syncthreads();
    if (tid == 0) {
        int acc = 0;
        for (int g = 0; g < G; g++) { gexc[g] = acc; acc += ghist[g]; }
    }
    __syncthreads();
    if (tid < G) {
        int c = ghist[tid];
        gbase[tid] = (c > 0) ? rs[tid * npg] + atomicAdd(&gcur[tid], c) : 0;
    }
    __syncthreads();
    for (int i = tid; i < n; i += 256) {
        int d = dst[e0 + i];
        int g = d / npg;
        int pos = gexc[g] + atomicAdd(&lcur[g], 1);
        ebuf[pos] = ((u32)src[e0 + i] << 16) | (u32)(d - g * npg);
        gmap[pos] = (u8)g;
    }
    __syncthreads();
    for (int i = tid; i < n; i += 256) {
        int g = gmap[i];
        tmp[gbase[g] + (i - gexc[g])] = ebuf[i];
    }
}

// ---- Pass B: one block per graph, counting-scatter to psrc via LDS cursors
__global__ __launch_bounds__(1024) void bucketB(const u32* __restrict__ tmp,
                                                const int* __restrict__ rs,
                                                int* __restrict__ psrc,
                                                int npg) {
    __shared__ int rsl[1025];
    __shared__ int lcur[1024];
    const int g = blockIdx.x, tid = threadIdx.x;
    const int base = g * npg;
    for (int i = tid; i <= npg; i += 1024) rsl[i] = rs[base + i];
    for (int i = tid; i < npg; i += 1024) lcur[i] = 0;
    __syncthreads();
    const int p0 = rsl[0], p1 = rsl[npg];
    for (int p = p0 + tid; p < p1; p += 1024) {
        u32 v = tmp[p];
        int dl = v & 0xffffu;
        int pos = rsl[dl] + atomicAdd(&lcur[dl], 1);
        psrc[pos] = (int)(v >> 16);
    }
}

// ---- fill pdst from CSR ranges (coalesced sequential writes)
__global__ void fill_pdst(const int* __restrict__ rs, int* __restrict__ pdst, int N) {
    int nid = blockIdx.x * 4 + (threadIdx.x >> 6);
    if (nid >= N) return;
    int lane = threadIdx.x & 63;
    int p0 = rs[nid], p1 = rs[nid + 1];
    for (int p = p0 + lane; p < p1; p += 64) pdst[p] = nid;
}

// ---- Gaussian weights in permuted order, all L layers, padded float4
__global__ void gw_kernel(const int* __restrict__ psrc, const int* __restrict__ pdst,
                          const int* __restrict__ cnt,
                          const float* __restrict__ ppW, const float* __restrict__ ppb,
                          const float* __restrict__ mu, const float* __restrict__ isig,
                          float* __restrict__ pgw, int E, int L) {
    int p = blockIdx.x * 256 + threadIdx.x;
    if (p >= E) return;
    float ps0 = rsqrtf((float)cnt[psrc[p]] + 1.0f);
    float ps1 = rsqrtf((float)cnt[pdst[p]] + 1.0f);
    for (int l = 0; l < L; l++) {
        float p0 = tanhf(ps0 * ppW[l * 4 + 0] + ps1 * ppW[l * 4 + 2] + ppb[l * 2 + 0]);
        float p1 = tanhf(ps0 * ppW[l * 4 + 1] + ps1 * ppW[l * 4 + 3] + ppb[l * 2 + 1]);
        float4 o;
        float* ov = (float*)&o;
#pragma unroll
        for (int k = 0; k < 3; k++) {
            float d0 = (p0 - mu[(l * 3 + k) * 2 + 0]) * isig[(l * 3 + k) * 2 + 0];
            float d1 = (p1 - mu[(l * 3 + k) * 2 + 1]) * isig[(l * 3 + k) * 2 + 1];
            ov[k] = expf(-0.5f * (d0 * d0 + d1 * d1));
        }
        o.w = 0.f;
        ((float4*)pgw)[(size_t)l * E + p] = o;
    }
}

// ---- per-node aggregation: one wave per node, 2 edges/iter (half-wave each),
//      main loop 8 pairs (16 edges) for deep MLP; final shfl_xor(32) reduce.
__global__ __launch_bounds__(256) void agg_kernel(const u16* __restrict__ hb,
                                                  const float* __restrict__ pgw,
                                                  const int* __restrict__ psrc,
                                                  const int* __restrict__ rs,
                                                  u16* __restrict__ t,
                                                  float* __restrict__ sk, int N) {
    int nid = blockIdx.x * 4 + (threadIdx.x >> 6);
    if (nid >= N) return;
    int lane = threadIdx.x & 63;
    int half = lane >> 5;
    int cl = lane & 31;
    int p0 = __builtin_amdgcn_readfirstlane(rs[nid]);
    int p1 = __builtin_amdgcn_readfirstlane(rs[nid + 1]);
    float a0[4] = {}, a1[4] = {}, a2[4] = {};
    float gs0 = 0.f, gs1 = 0.f, gs2 = 0.f;
    const float4* pg4 = (const float4*)pgw;
    int p = p0;
    // 8 pairs (16 edges) per iteration
    for (; p + 16 <= p1; p += 16) {
        int s[8];
        uint2 hv[8];
        float4 g[8];
#pragma unroll
        for (int q = 0; q < 4; q++) {
            int4 sa = *(const int4*)(psrc + p + q * 4);
            s[2 * q]     = half ? sa.y : sa.x;
            s[2 * q + 1] = half ? sa.w : sa.z;
        }
#pragma unroll
        for (int j = 0; j < 8; j++)
            hv[j] = *(const uint2*)(hb + (size_t)s[j] * 128 + cl * 4);
#pragma unroll
        for (int j = 0; j < 8; j++)
            g[j] = pg4[p + 2 * j + half];
#pragma unroll
        for (int j = 0; j < 8; j++) {
            float f0 = blo(hv[j].x), f1 = bhi(hv[j].x), f2 = blo(hv[j].y), f3 = bhi(hv[j].y);
            a0[0] += g[j].x * f0; a0[1] += g[j].x * f1; a0[2] += g[j].x * f2; a0[3] += g[j].x * f3;
            a1[0] += g[j].y * f0; a1[1] += g[j].y * f1; a1[2] += g[j].y * f2; a1[3] += g[j].y * f3;
            a2[0] += g[j].z * f0; a2[1] += g[j].z * f1; a2[2] += g[j].z * f2; a2[3] += g[j].z * f3;
            gs0 += g[j].x; gs1 += g[j].y; gs2 += g[j].z;
        }
    }
    // remaining pairs
    for (; p + 2 <= p1; p += 2) {
        int2 sa = *(const int2*)(psrc + p);
        int s0 = half ? sa.y : sa.x;
        uint2 hv = *(const uint2*)(hb + (size_t)s0 * 128 + cl * 4);
        float4 g = pg4[p + half];
        float f0 = blo(hv.x), f1 = bhi(hv.x), f2 = blo(hv.y), f3 = bhi(hv.y);
        a0[0] += g.x * f0; a0[1] += g.x * f1; a0[2] += g.x * f2; a0[3] += g.x * f3;
        a1[0] += g.y * f0; a1[1] += g.y * f1; a1[2] += g.y * f2; a1[3] += g.y * f3;
        a2[0] += g.z * f0; a2[1] += g.z * f1; a2[2] += g.z * f2; a2[3] += g.z * f3;
        gs0 += g.x; gs1 += g.y; gs2 += g.z;
    }
    // odd tail edge: only half 0 accumulates
    if (p < p1) {
        int s0 = psrc[p];
        uint2 hv = *(const uint2*)(hb + (size_t)s0 * 128 + cl * 4);
        float4 g = pg4[p];
        float msk = half ? 0.f : 1.f;
        float gx = g.x * msk, gy = g.y * msk, gz = g.z * msk;
        float f0 = blo(hv.x), f1 = bhi(hv.x), f2 = blo(hv.y), f3 = bhi(hv.y);
        a0[0] += gx * f0; a0[1] += gx * f1; a0[2] += gx * f2; a0[3] += gx * f3;
        a1[0] += gy * f0; a1[1] += gy * f1; a1[2] += gy * f2; a1[3] += gy * f3;
        a2[0] += gz * f0; a2[1] += gz * f1; a2[2] += gz * f2; a2[3] += gz * f3;
        gs0 += gx; gs1 += gy; gs2 += gz;
    }
#pragma unroll
    for (int c = 0; c < 4; c++) {
        a0[c] += __shfl_xor(a0[c], 32);
        a1[c] += __shfl_xor(a1[c], 32);
        a2[c] += __shfl_xor(a2[c], 32);
    }
    gs0 += __shfl_xor(gs0, 32);
    gs1 += __shfl_xor(gs1, 32);
    gs2 += __shfl_xor(gs2, 32);
    if (half == 0) {
        size_t base = (size_t)nid * 384 + cl * 4;
        ushort4 o0, o1, o2;
        o0.x = f2b(a0[0]); o0.y = f2b(a0[1]); o0.z = f2b(a0[2]); o0.w = f2b(a0[3]);
        o1.x = f2b(a1[0]); o1.y = f2b(a1[1]); o1.z = f2b(a1[2]); o1.w = f2b(a1[3]);
        o2.x = f2b(a2[0]); o2.y = f2b(a2[1]); o2.z = f2b(a2[2]); o2.w = f2b(a2[3]);
        *(ushort4*)(t + base)       = o0;
        *(ushort4*)(t + base + 128) = o1;
        *(ushort4*)(t + base + 256) = o2;
        if (cl == 0) {
            sk[nid * 4 + 0] = gs0;
            sk[nid * 4 + 1] = gs1;
            sk[nid * 4 + 2] = gs2;
            sk[nid * 4 + 3] = 0.f;
        }
    }
}

// ---- bf16 MFMA GEMM: out[M,128] = A[M,KD] @ Bt[128,KD]^T (+ epilogue)
//   mode 0 (embed): v = acc + bias[col]; h(outF)=v; hb(outB)=bf16(v)
//   mode 1 (fc):    v = acc + sum_k sk[row,k]*bias[k*128+col]; outB=bf16(v);
//                   per-channel sum/sumsq (fp32) reduced into bnred[0:256]
__global__ __launch_bounds__(256) void gemm_mfma(const u16* __restrict__ A,
                                                 const u16* __restrict__ Bt,
                                                 int M, int KD,
                                                 const float* __restrict__ bias,
                                                 const float* __restrict__ sk,
                                                 float* __restrict__ outF,
                                                 u16* __restrict__ outB,
                                                 int mode,
                                                 float* __restrict__ bnred) {
    __shared__ u16 As[128 * 64];
    __shared__ u16 Bs[128 * 64];
    const int m0 = blockIdx.x * 128;
    const int tid = threadIdx.x;
    const int lane = tid & 63;
    const int w = tid >> 6;
    const int wr = w >> 1, wc = w & 1;

    f32x4 acc[4][4];
#pragma unroll
    for (int m = 0; m < 4; m++)
#pragma unroll
        for (int n = 0; n < 4; n++) acc[m][n] = (f32x4){0.f, 0.f, 0.f, 0.f};

    for (int k0 = 0; k0 < KD; k0 += 64) {
        __syncthreads();
#pragma unroll
        for (int i = 0; i < 4; i++) {
            int idx = tid + i * 256;
            int r = idx >> 3, g = idx & 7;
            int gs = g ^ (r & 7);
            uint4 av = make_uint4(0, 0, 0, 0);
            if (m0 + r < M) av = *(const uint4*)(A + (size_t)(m0 + r) * KD + k0 + g * 8);
            *(uint4*)(As + r * 64 + gs * 8) = av;
            uint4 bv = *(const uint4*)(Bt + (size_t)r * KD + k0 + g * 8);
            *(uint4*)(Bs + r * 64 + gs * 8) = bv;
        }
        __syncthreads();
#pragma unroll
        for (int kk = 0; kk < 2; kk++) {
            bf16x8 af[4], bfr[4];
#pragma unroll
            for (int m = 0; m < 4; m++) {
                int r = wr * 64 + m * 16 + (lane & 15);
                int g = (kk * 4 + (lane >> 4)) ^ (r & 7);
                af[m] = *(const bf16x8*)(As + r * 64 + g * 8);
            }
#pragma unroll
            for (int n = 0; n < 4; n++) {
                int r = wc * 64 + n * 16 + (lane & 15);
                int g = (kk * 4 + (lane >> 4)) ^ (r & 7);
                bfr[n] = *(const bf16x8*)(Bs + r * 64 + g * 8);
            }
#pragma unroll
            for (int m = 0; m < 4; m++)
#pragma unroll
                for (int n = 0; n < 4; n++)
                    acc[m][n] = __builtin_amdgcn_mfma_f32_16x16x32_bf16(af[m], bfr[n], acc[m][n], 0, 0, 0);
        }
    }

    if (mode == 0) {
#pragma unroll
        for (int n = 0; n < 4; n++) {
            int col = wc * 64 + n * 16 + (lane & 15);
            float bv = bias[col];
#pragma unroll
            for (int m = 0; m < 4; m++) {
#pragma unroll
                for (int j = 0; j < 4; j++) {
                    int row = m0 + wr * 64 + m * 16 + (lane >> 4) * 4 + j;
                    if (row < M) {
                        float v = acc[m][n][j] + bv;
                        outF[(size_t)row * 128 + col] = v;
                        outB[(size_t)row * 128 + col] = f2b(v);
                    }
                }
            }
        }
    } else {
        float colsum[4] = {0.f, 0.f, 0.f, 0.f};
        float colsq[4]  = {0.f, 0.f, 0.f, 0.f};
#pragma unroll
        for (int n = 0; n < 4; n++) {
            int col = wc * 64 + n * 16 + (lane & 15);
            float b0 = bias[col], b1 = bias[128 + col], b2 = bias[256 + col];
#pragma unroll
            for (int m = 0; m < 4; m++) {
#pragma unroll
                for (int j = 0; j < 4; j++) {
                    int row = m0 + wr * 64 + m * 16 + (lane >> 4) * 4 + j;
                    if (row < M) {
                        float4 skv = *(const float4*)(sk + row * 4);
                        float v = acc[m][n][j] + skv.x * b0 + skv.y * b1 + skv.z * b2;
                        outB[(size_t)row * 128 + col] = f2b(v);
                        colsum[n] += v;
                        colsq[n]  += v * v;
                    }
                }
            }
        }
        __syncthreads();
        float* red = (float*)As;         // 256 floats: [0:128] sum, [128:256] sq
        if (tid < 256) red[tid] = 0.f;
        __syncthreads();
#pragma unroll
        for (int n = 0; n < 4; n++) {
            float s = colsum[n], q = colsq[n];
            s += __shfl_xor(s, 16); s += __shfl_xor(s, 32);
            q += __shfl_xor(q, 16); q += __shfl_xor(q, 32);
            if (lane < 16) {
                int col = wc * 64 + n * 16 + lane;
                atomicAdd(&red[col], s);
                atomicAdd(&red[128 + col], q);
            }
        }
        __syncthreads();
        if (tid < 256) atomicAdd(&bnred[tid], red[tid]);
    }
}

// ---- h = h + relu((aggB-mean)*rstd*gamma + beta); aggB is bf16
__global__ void bn_apply(float* __restrict__ h, u16* __restrict__ hb,
                         const u16* __restrict__ aggB,
                         const float* __restrict__ bnred,
                         const float* __restrict__ gamma, const float* __restrict__ beta,
                         float invN, int N) {
    int idx = blockIdx.x * 256 + threadIdx.x;   // 4-channel index
    if (idx >= N * 32) return;
    int c4 = idx & 31;
    float4 s  = *(const float4*)(bnred + c4 * 4);
    float4 q  = *(const float4*)(bnred + 128 + c4 * 4);
    float4 ga = *(const float4*)(gamma + c4 * 4);
    float4 be = *(const float4*)(beta + c4 * 4);
    float4 sc, sh;
    {
        float m, v2;
        m = s.x * invN; v2 = q.x * invN - m * m; sc.x = ga.x * rsqrtf(v2 + 1e-5f); sh.x = be.x - m * sc.x;
        m = s.y * invN; v2 = q.y * invN - m * m; sc.y = ga.y * rsqrtf(v2 + 1e-5f); sh.y = be.y - m * sc.y;
        m = s.z * invN; v2 = q.z * invN - m * m; sc.z = ga.z * rsqrtf(v2 + 1e-5f); sh.z = be.z - m * sc.z;
        m = s.w * invN; v2 = q.w * invN - m * m; sc.w = ga.w * rsqrtf(v2 + 1e-5f); sh.w = be.w - m * sc.w;
    }
    u32 a01 = ((const u32*)aggB)[idx * 2];
    u32 a23 = ((const u32*)aggB)[idx * 2 + 1];
    float4 a = make_float4(blo(a01), bhi(a01), blo(a23), bhi(a23));
    float4 hv = ((float4*)h)[idx];
    hv.x += fmaxf(a.x * sc.x + sh.x, 0.f);
    hv.y += fmaxf(a.y * sc.y + sh.y, 0.f);
    hv.z += fmaxf(a.z * sc.z + sh.z, 0.f);
    hv.w += fmaxf(a.w * sc.w + sh.w, 0.f);
    ((float4*)h)[idx] = hv;
    ushort4 o; o.x = f2b(hv.x); o.y = f2b(hv.y); o.z = f2b(hv.z); o.w = f2b(hv.w);
    ((ushort4*)hb)[idx] = o;
}

// ---- per-graph sums: 25 rows per block (graph_ids sorted; flush-on-change)
__global__ void readout_kernel(const float* __restrict__ h, const int* __restrict__ gids,
                               float* __restrict__ hg, float* __restrict__ cnts, int N) {
    int c = threadIdx.x;
    int r0 = blockIdx.x * 25;
    if (r0 >= N) return;
    int r1 = min(r0 + 25, N);
    int cur = gids[r0];
    float acc = 0.f, cnt = 0.f;
    for (int r = r0; r < r1; r++) {
        int g = gids[r];
        if (g != cur) {
            atomicAdd(&hg[(size_t)cur * 128 + c], acc);
            if (c == 0) atomicAdd(&cnts[cur], cnt);
            acc = 0.f; cnt = 0.f; cur = g;
        }
        acc += h[(size_t)r * 128 + c];
        cnt += 1.f;
    }
    atomicAdd(&hg[(size_t)cur * 128 + c], acc);
    if (c == 0) atomicAdd(&cnts[cur], cnt);
}

// ---- MLP readout
__global__ void mlp_kernel(const float* __restrict__ hg, const float* __restrict__ cnts,
                           const float* __restrict__ W1, const float* __restrict__ b1,
                           const float* __restrict__ W2, const float* __restrict__ b2,
                           const float* __restrict__ W3, const float* __restrict__ b3,
                           float* __restrict__ out) {
    __shared__ float v[128], y1[64], y2[32];
    int g = blockIdx.x, t = threadIdx.x;
    float inv = 1.0f / cnts[g];
    v[t] = hg[(size_t)g * 128 + t] * inv;
    __syncthreads();
    if (t < 64) {
        float a = b1[t];
        for (int k = 0; k < 128; k++) a += v[k] * W1[k * 64 + t];
        y1[t] = fmaxf(a, 0.f);
    }
    __syncthreads();
    if (t < 32) {
        float a = b2[t];
        for (int k = 0; k < 64; k++) a += y1[k] * W2[k * 32 + t];
        y2[t] = fmaxf(a, 0.f);
    }
    __syncthreads();
    if (t < 10) {
        float a = b3[t];
        for (int k = 0; k < 32; k++) a += y2[k] * W3[k * 10 + t];
        out[g * 10 + t] = a;
    }
}

extern "C" void kernel_launch(void* const* d_in, const int* in_sizes, int n_in,
                              void* d_out, int out_size, void* d_ws, size_t ws_size,
                              hipStream_t stream) {
    const float* x      = (const float*)d_in[0];
    const float* emb_W  = (const float*)d_in[1];
    const float* emb_b  = (const float*)d_in[2];
    const float* fc_W   = (const float*)d_in[3];
    const float* fc_b   = (const float*)d_in[4];
    const float* mu     = (const float*)d_in[5];
    const float* isig   = (const float*)d_in[6];
    const float* gamma  = (const float*)d_in[7];
    const float* beta   = (const float*)d_in[8];
    const float* ppW    = (const float*)d_in[9];
    const float* ppb    = (const float*)d_in[10];
    const float* W1     = (const float*)d_in[11];
    const float* b1     = (const float*)d_in[12];
    const float* W2     = (const float*)d_in[13];
    const float* b2     = (const float*)d_in[14];
    const float* W3     = (const float*)d_in[15];
    const float* b3     = (const float*)d_in[16];
    const int*   src    = (const int*)d_in[17];
    const int*   dst    = (const int*)d_in[18];
    const int*   gids   = (const int*)d_in[19];

    const int N = in_sizes[0] / 128;
    const int E = in_sizes[17];
    const int L = in_sizes[8] / 128;
    const int G = out_size / 10;
    const int npg = N / G;                 // 1000
    float* out = (float*)d_out;

    char* wp = (char*)d_ws;
    auto alloc = [&](size_t bytes) {
        char* p = wp;
        wp += (bytes + 255) & ~(size_t)255;
        return (void*)p;
    };
    float* h      = (float*)alloc((size_t)N * 128 * 4);
    u16*   hb     = (u16*)alloc((size_t)N * 128 * 2);
    u16*   t      = (u16*)alloc((size_t)N * 384 * 2);
    u16*   aggB   = (u16*)alloc((size_t)N * 128 * 2);
    float* pgw    = (float*)alloc((size_t)L * E * 4 * 4);
    int*   psrc   = (int*)alloc((size_t)E * 4);
    int*   pdst   = (int*)alloc((size_t)E * 4);
    u32*   tmp    = (u32*)alloc((size_t)E * 4);
    float* sk     = (float*)alloc((size_t)N * 4 * 4);
    int*   cnt    = (int*)alloc((size_t)N * 4);
    int*   rs     = (int*)alloc((size_t)(N + 1) * 4);
    int*   gcur   = (int*)alloc(256 * 4);
    int*   bsum   = (int*)alloc(256 * 4);
    int*   boff   = (int*)alloc(256 * 4);
    u16*   wembt  = (u16*)alloc((size_t)128 * 128 * 2);
    u16*   wfct   = (u16*)alloc((size_t)L * 128 * 384 * 2);
    float* bnAll  = (float*)alloc((size_t)L * 256 * 4);
    float* hg     = (float*)alloc((size_t)G * 128 * 4);
    float* cnts   = (float*)alloc((size_t)G * 4);
    u16*   xb     = (u16*)t;   // overlay: xb only needed before first agg

    hipMemsetAsync(cnt, 0, (size_t)N * 4, stream);
    hipMemsetAsync(gcur, 0, 256 * 4, stream);
    hipMemsetAsync(hg, 0, (size_t)G * 128 * 4, stream);
    hipMemsetAsync(cnts, 0, (size_t)G * 4, stream);
    hipMemsetAsync(bnAll, 0, (size_t)L * 256 * 4, stream);

    // conversions + weight prep
    cvt_bf16<<<(N * 32 + 255) / 256, 256, 0, stream>>>(x, xb, N * 32);
    prep_embW<<<(128 * 128 + 255) / 256, 256, 0, stream>>>(emb_W, wembt);
    prep_fcW<<<(L * 128 * 384 + 255) / 256, 256, 0, stream>>>(fc_W, wfct, L * 128 * 384);

    // CSR build: hist -> scan -> graph-bucket passes
    const int nb = (N + 255) / 256;
    hist_kernel<<<(E + 255) / 256, 256, 0, stream>>>(dst, cnt, E);
    scan_partial<<<nb, 256, 0, stream>>>(cnt, bsum, N);
    scan_bsums<<<1, 256, 0, stream>>>(bsum, boff, nb);
    scan_final<<<nb, 256, 0, stream>>>(cnt, boff, rs, N);
    bucketA<<<(E + 4095) / 4096, 256, 0, stream>>>(src, dst, rs, gcur, tmp, E, npg, G);
    bucketB<<<G, 1024, 0, stream>>>(tmp, rs, psrc, npg);
    fill_pdst<<<(N + 3) / 4, 256, 0, stream>>>(rs, pdst, N);
    gw_kernel<<<(E + 255) / 256, 256, 0, stream>>>(psrc, pdst, cnt, ppW, ppb, mu, isig, pgw, E, L);

    // node embedding
    const int gblocks = (N + 127) / 128;
    gemm_mfma<<<gblocks, 256, 0, stream>>>(xb, wembt, N, 128, emb_b, nullptr, h, hb, 0, nullptr);

    const float invN = 1.0f / (float)N;
    for (int l = 0; l < L; l++) {
        agg_kernel<<<(N + 3) / 4, 256, 0, stream>>>(hb, pgw + (size_t)l * E * 4, psrc, rs, t, sk, N);
        gemm_mfma<<<gblocks, 256, 0, stream>>>(t, wfct + (size_t)l * 128 * 384, N, 384,
                                               fc_b + (size_t)l * 384, sk, nullptr, aggB, 1,
                                               bnAll + (size_t)l * 256);
        bn_apply<<<(N * 32 + 255) / 256, 256, 0, stream>>>(h, hb, aggB, bnAll + (size_t)l * 256,
                                                           gamma + l * 128, beta + l * 128, invN, N);
    }

    readout_kernel<<<(N + 24) / 25, 128, 0, stream>>>(h, gids, hg, cnts, N);
    mlp_kernel<<<G, 128, 0, stream>>>(hg, cnts, W1, b1, W2, b2, W3, b3, out);
}